// Round 1
// baseline (7413.324 us; speedup 1.0000x reference)
//
#include <hip/hip_runtime.h>

#define HD 128

__device__ __forceinline__ float f4c(const float4& v, int q) {
  return q == 0 ? v.x : q == 1 ? v.y : q == 2 ? v.z : v.w;
}

// ---- per-edge prep: degree (as float) + dist = pos[src]-pos[dst] ----------
__global__ void edge_prep_k(const int* __restrict__ ei, const float* __restrict__ pos,
                            float* __restrict__ deg, float* __restrict__ dist, int E) {
  int e = blockIdx.x * 256 + threadIdx.x;
  if (e >= E) return;
  int s = ei[e], d = ei[E + e];
  atomicAdd(&deg[d], 1.0f);
  dist[(size_t)e*3+0] = pos[(size_t)s*3+0] - pos[(size_t)d*3+0];
  dist[(size_t)e*3+1] = pos[(size_t)s*3+1] - pos[(size_t)d*3+1];
  dist[(size_t)e*3+2] = pos[(size_t)s*3+2] - pos[(size_t)d*3+2];
}

__global__ void invdeg_k(float* __restrict__ deg, int n) {
  int i = blockIdx.x * 256 + threadIdx.x;
  if (i < n) { float v = deg[i]; deg[i] = v > 0.f ? 1.f / v : 0.f; }
}

// ---- h1 = relu(x * w1 + b1)  (K=1 layer) ----------------------------------
__global__ void node_init_k(const float* __restrict__ x, const float* __restrict__ w1,
                            const float* __restrict__ b1, float* __restrict__ h1, int n) {
  int i = blockIdx.x * 2 + (threadIdx.x >> 7);
  int j = threadIdx.x & 127;
  if (i >= n) return;
  float v = fmaf(x[i], w1[j], b1[j]);
  h1[(size_t)i*HD + j] = v > 0.f ? v : 0.f;
}

// ---- Wfold = w3_2 @ W2b ; ubias = b2_1 + b3_2 @ W2b ------------------------
__global__ void fold_k(const float* __restrict__ w32, const float* __restrict__ w2b,
                       const float* __restrict__ b32, const float* __restrict__ b21,
                       float* __restrict__ Wf, float* __restrict__ ub) {
  int k = blockIdx.x, c = threadIdx.x;
  float s = 0.f;
  for (int r = 0; r < 128; ++r) s = fmaf(w32[k*128 + r], w2b[r*128 + c], s);
  Wf[k*128 + c] = s;
  if (k == 0) {
    float t = b21[c];
    for (int r = 0; r < 128; ++r) t = fmaf(b32[r], w2b[r*128 + c], t);
    ub[c] = t;
  }
}

// ---- generic node GEMM: out[M][128] = act(concat-A @ W[K][128] + bias) -----
// A row m = (SCALE0 ? sc[m]*in0[m] : in0[m]) for k<128, in1[m] for k>=128.
template<int K, bool RELU, bool SCALE0>
__global__ __launch_bounds__(256) void gemm_node(
    const float* __restrict__ in0, const float* __restrict__ in1,
    const float* __restrict__ sc, const float* __restrict__ W,
    const float* __restrict__ bias, float* __restrict__ out, int M)
{
  __shared__ float A[16][132];
  __shared__ float B[16][132];
  const int tid = threadIdx.x;
  const int ty = tid >> 4, tx = tid & 15;
  const int m0 = blockIdx.x * 128;

  float acc[8][8];
#pragma unroll
  for (int i = 0; i < 8; ++i)
#pragma unroll
    for (int j = 0; j < 8; ++j) acc[i][j] = 0.f;

  for (int kc = 0; kc < K; kc += 16) {
    __syncthreads();
    { // stage A chunk (transposed to [k][m])
      int m = tid >> 1, kh = (tid & 1) * 8;
      int gm = m0 + m, kk = kc + kh;
      float4 v0 = {0,0,0,0}, v1 = {0,0,0,0};
      if (gm < M) {
        const float* base = (K == 256 && kk >= 128) ? (in1 + (size_t)gm*HD + (kk - 128))
                                                    : (in0 + (size_t)gm*HD + kk);
        v0 = *(const float4*)base;
        v1 = *(const float4*)(base + 4);
        if (SCALE0 && kk < 128) {
          float s = sc[gm];
          v0.x*=s; v0.y*=s; v0.z*=s; v0.w*=s;
          v1.x*=s; v1.y*=s; v1.z*=s; v1.w*=s;
        }
      }
      A[kh+0][m] = v0.x; A[kh+1][m] = v0.y; A[kh+2][m] = v0.z; A[kh+3][m] = v0.w;
      A[kh+4][m] = v1.x; A[kh+5][m] = v1.y; A[kh+6][m] = v1.z; A[kh+7][m] = v1.w;
    }
    { // stage B chunk
      int k = tid >> 4, c = (tid & 15) * 8;
      *(float4*)&B[k][c]   = *(const float4*)&W[(size_t)(kc+k)*HD + c];
      *(float4*)&B[k][c+4] = *(const float4*)&W[(size_t)(kc+k)*HD + c + 4];
    }
    __syncthreads();
#pragma unroll
    for (int kk = 0; kk < 16; ++kk) {
      float4 a0 = *(const float4*)&A[kk][ty*8];
      float4 a1 = *(const float4*)&A[kk][ty*8+4];
      float4 b0 = *(const float4*)&B[kk][tx*8];
      float4 b1 = *(const float4*)&B[kk][tx*8+4];
      float av[8] = {a0.x,a0.y,a0.z,a0.w,a1.x,a1.y,a1.z,a1.w};
      float bv[8] = {b0.x,b0.y,b0.z,b0.w,b1.x,b1.y,b1.z,b1.w};
#pragma unroll
      for (int i = 0; i < 8; ++i)
#pragma unroll
        for (int j = 0; j < 8; ++j) acc[i][j] = fmaf(av[i], bv[j], acc[i][j]);
    }
  }

  float bv[8];
  if (bias) {
    float4 b0 = *(const float4*)&bias[tx*8];
    float4 b1 = *(const float4*)&bias[tx*8+4];
    bv[0]=b0.x; bv[1]=b0.y; bv[2]=b0.z; bv[3]=b0.w;
    bv[4]=b1.x; bv[5]=b1.y; bv[6]=b1.z; bv[7]=b1.w;
  } else {
#pragma unroll
    for (int j = 0; j < 8; ++j) bv[j] = 0.f;
  }
#pragma unroll
  for (int i = 0; i < 8; ++i) {
    int gm = m0 + ty*8 + i;
    if (gm < M) {
      float o[8];
#pragma unroll
      for (int j = 0; j < 8; ++j) {
        float v = acc[i][j] + bv[j];
        o[j] = (RELU && v < 0.f) ? 0.f : v;
      }
      float4 s0 = {o[0],o[1],o[2],o[3]}, s1 = {o[4],o[5],o[6],o[7]};
      *(float4*)&out[(size_t)gm*HD + tx*8]     = s0;
      *(float4*)&out[(size_t)gm*HD + tx*8 + 4] = s1;
    }
  }
}

// ---- fused edge kernel: t -> u -> pre -> msg -> atomic scatter -------------
__global__ __launch_bounds__(256) void edge_k(
    const int* __restrict__ ei, const float* __restrict__ dist,
    const float* __restrict__ hA,
    const float* __restrict__ w31, const float* __restrict__ b31,
    const float* __restrict__ Wf, const float* __restrict__ ub,
    const float* __restrict__ w22, const float* __restrict__ b22,
    float* __restrict__ agg, int E)
{
  __shared__ float T[128][132];   // t as [k][e], then pre as [e][c]
  __shared__ float WC[16][132];   // weight K-chunk
  const int tid = threadIdx.x;
  const int ty = tid >> 4, tx = tid & 15;
  const int e0 = blockIdx.x * 128;

  // stage 1: T[k][e] = relu(dist[e] . w31[:,k] + b31[k])
  {
    int el = tid & 127;
    int e = e0 + el;
    float d0 = 0.f, d1 = 0.f, d2 = 0.f;
    if (e < E) {
      d0 = dist[(size_t)e*3+0];
      d1 = dist[(size_t)e*3+1];
      d2 = dist[(size_t)e*3+2];
    }
    int k0 = (tid >> 7) * 64;
#pragma unroll 4
    for (int k = k0; k < k0 + 64; ++k) {
      float v = fmaf(d0, w31[k], fmaf(d1, w31[128+k], fmaf(d2, w31[256+k], b31[k])));
      T[k][el] = v > 0.f ? v : 0.f;
    }
  }

  float acc[8][8];
#pragma unroll
  for (int i = 0; i < 8; ++i)
#pragma unroll
    for (int j = 0; j < 8; ++j) acc[i][j] = 0.f;

  // stage 2: u = t @ Wfold   (rows: edges e0+ty*8+i, cols: tx*8+j)
  for (int kc = 0; kc < 128; kc += 16) {
    __syncthreads();
    {
      int lk = tid >> 4, lc = (tid & 15) * 8;
      *(float4*)&WC[lk][lc]   = *(const float4*)&Wf[(size_t)(kc+lk)*HD + lc];
      *(float4*)&WC[lk][lc+4] = *(const float4*)&Wf[(size_t)(kc+lk)*HD + lc + 4];
    }
    __syncthreads();
#pragma unroll
    for (int kk = 0; kk < 16; ++kk) {
      float4 a0 = *(const float4*)&T[kc+kk][ty*8];
      float4 a1 = *(const float4*)&T[kc+kk][ty*8+4];
      float4 b0 = *(const float4*)&WC[kk][tx*8];
      float4 b1 = *(const float4*)&WC[kk][tx*8+4];
      float av[8] = {a0.x,a0.y,a0.z,a0.w,a1.x,a1.y,a1.z,a1.w};
      float bv[8] = {b0.x,b0.y,b0.z,b0.w,b1.x,b1.y,b1.z,b1.w};
#pragma unroll
      for (int i = 0; i < 8; ++i)
#pragma unroll
        for (int j = 0; j < 8; ++j) acc[i][j] = fmaf(av[i], bv[j], acc[i][j]);
    }
  }
  __syncthreads();

  // stage 3: pre = relu(u + hA[src] + ubias) -> T[e][c]
  {
    float4 u0 = *(const float4*)&ub[tx*8];
    float4 u1 = *(const float4*)&ub[tx*8+4];
    float ubv[8] = {u0.x,u0.y,u0.z,u0.w,u1.x,u1.y,u1.z,u1.w};
#pragma unroll
    for (int i = 0; i < 8; ++i) {
      int e = e0 + ty*8 + i;
      float hv[8] = {0,0,0,0,0,0,0,0};
      if (e < E) {
        int s = ei[e];
        float4 h0 = *(const float4*)&hA[(size_t)s*HD + tx*8];
        float4 h1 = *(const float4*)&hA[(size_t)s*HD + tx*8 + 4];
        hv[0]=h0.x; hv[1]=h0.y; hv[2]=h0.z; hv[3]=h0.w;
        hv[4]=h1.x; hv[5]=h1.y; hv[6]=h1.z; hv[7]=h1.w;
      }
      float pr[8];
#pragma unroll
      for (int j = 0; j < 8; ++j) {
        float v = acc[i][j] + hv[j] + ubv[j];
        pr[j] = v > 0.f ? v : 0.f;
      }
      float4 s0 = {pr[0],pr[1],pr[2],pr[3]}, s1 = {pr[4],pr[5],pr[6],pr[7]};
      *(float4*)&T[ty*8+i][tx*8]     = s0;
      *(float4*)&T[ty*8+i][tx*8 + 4] = s1;
    }
  }

#pragma unroll
  for (int i = 0; i < 8; ++i)
#pragma unroll
    for (int j = 0; j < 8; ++j) acc[i][j] = 0.f;

  // stage 4: msg = pre @ w2_2
  for (int kc = 0; kc < 128; kc += 16) {
    __syncthreads();
    {
      int lk = tid >> 4, lc = (tid & 15) * 8;
      *(float4*)&WC[lk][lc]   = *(const float4*)&w22[(size_t)(kc+lk)*HD + lc];
      *(float4*)&WC[lk][lc+4] = *(const float4*)&w22[(size_t)(kc+lk)*HD + lc + 4];
    }
    __syncthreads();
#pragma unroll
    for (int kk = 0; kk < 16; kk += 4) {
      float4 a4[8];
#pragma unroll
      for (int i = 0; i < 8; ++i) a4[i] = *(const float4*)&T[ty*8+i][kc+kk];
#pragma unroll
      for (int q = 0; q < 4; ++q) {
        float4 b0 = *(const float4*)&WC[kk+q][tx*8];
        float4 b1 = *(const float4*)&WC[kk+q][tx*8+4];
        float bv[8] = {b0.x,b0.y,b0.z,b0.w,b1.x,b1.y,b1.z,b1.w};
#pragma unroll
        for (int i = 0; i < 8; ++i) {
          float a = f4c(a4[i], q);
#pragma unroll
          for (int j = 0; j < 8; ++j) acc[i][j] = fmaf(a, bv[j], acc[i][j]);
        }
      }
    }
  }

  // epilogue: agg[dst] += msg + b2_2
  {
    float4 c0 = *(const float4*)&b22[tx*8];
    float4 c1 = *(const float4*)&b22[tx*8+4];
    float bb[8] = {c0.x,c0.y,c0.z,c0.w,c1.x,c1.y,c1.z,c1.w};
#pragma unroll
    for (int i = 0; i < 8; ++i) {
      int e = e0 + ty*8 + i;
      if (e < E) {
        int d = ei[E + e];
        float* dst = &agg[(size_t)d*HD + tx*8];
#pragma unroll
        for (int j = 0; j < 8; ++j) atomicAdd(&dst[j], acc[i][j] + bb[j]);
      }
    }
  }
}

// ---- readout: y = relu(h@lin1+b1)@lin2+b2 ; out[batch[i]] += y -------------
__global__ __launch_bounds__(256) void readout_k(
    const float* __restrict__ h, const float* __restrict__ l1w, const float* __restrict__ l1b,
    const float* __restrict__ l2w, const float* __restrict__ l2b,
    const int* __restrict__ batch, float* __restrict__ out, int n)
{
  int node = blockIdx.x * 4 + (threadIdx.x >> 6);
  int lane = threadIdx.x & 63;
  if (node >= n) return;
  const float* hr = h + (size_t)node * HD;
  float z = l1b[lane];
  for (int k = 0; k < 128; ++k) z = fmaf(hr[k], l1w[k*64 + lane], z);
  float t = z > 0.f ? z * l2w[lane] : 0.f;
#pragma unroll
  for (int off = 32; off > 0; off >>= 1) t += __shfl_down(t, off);
  if (lane == 0) atomicAdd(&out[batch[node]], t + l2b[0]);
}

extern "C" void kernel_launch(void* const* d_in, const int* in_sizes, int n_in,
                              void* d_out, int out_size, void* d_ws, size_t ws_size,
                              hipStream_t stream) {
  const float* x     = (const float*)d_in[0];
  const float* pos   = (const float*)d_in[1];
  const int*   ei    = (const int*)d_in[2];
  const int*   batch = (const int*)d_in[3];
  const float* nw1   = (const float*)d_in[4];
  const float* nb1   = (const float*)d_in[5];
  const float* nw2   = (const float*)d_in[6];
  const float* nb2   = (const float*)d_in[7];
  const float* m1w1  = (const float*)d_in[8];
  const float* m1b1  = (const float*)d_in[9];
  const float* m1w2  = (const float*)d_in[10];
  const float* m1b2  = (const float*)d_in[11];
  const float* m2w1  = (const float*)d_in[12];
  const float* m2b1  = (const float*)d_in[13];
  const float* m2w2  = (const float*)d_in[14];
  const float* m2b2  = (const float*)d_in[15];
  const float* m3w1  = (const float*)d_in[16];
  const float* m3b1  = (const float*)d_in[17];
  const float* m3w2  = (const float*)d_in[18];
  // d_in[19] = mlp3_b2 — folded into ubias via fold_k
  const float* m3b2  = (const float*)d_in[19];
  const float* l1w   = (const float*)d_in[20];
  const float* l1b   = (const float*)d_in[21];
  const float* l2w   = (const float*)d_in[22];
  const float* l2b   = (const float*)d_in[23];

  const int N = in_sizes[0];
  const int E = in_sizes[2] / 2;
  const int L = in_sizes[8] / (256 * 128);

  float* h    = (float*)d_ws;                 // [N,128]
  float* buf2 = h    + (size_t)N * HD;        // h1 / hA / tmp  [N,128]
  float* agg  = buf2 + (size_t)N * HD;        // [N,128]
  float* dist = agg  + (size_t)N * HD;        // [E,3]
  float* invd = dist + (size_t)E * 3;         // [N]
  float* Wf   = invd + N;                     // [128,128]
  float* ub   = Wf   + 128 * 128;             // [128]

  hipMemsetAsync(invd, 0, (size_t)N * sizeof(float), stream);
  hipMemsetAsync(d_out, 0, (size_t)out_size * sizeof(float), stream);

  edge_prep_k<<<(E + 255) / 256, 256, 0, stream>>>(ei, pos, invd, dist, E);
  invdeg_k<<<(N + 255) / 256, 256, 0, stream>>>(invd, N);
  node_init_k<<<(N + 1) / 2, 256, 0, stream>>>(x, nw1, nb1, buf2, N);
  gemm_node<128, false, false><<<(N + 127) / 128, 256, 0, stream>>>(
      buf2, nullptr, nullptr, nw2, nb2, h, N);

  for (int l = 0; l < L; ++l) {
    const float* W2a = m2w1 + (size_t)l * 256 * 128;        // rows 0..127
    const float* W2b = W2a + 128 * 128;                     // rows 128..255
    fold_k<<<128, 128, 0, stream>>>(m3w2 + (size_t)l * 128 * 128, W2b,
                                    m3b2 + (size_t)l * 128, m2b1 + (size_t)l * 128, Wf, ub);
    gemm_node<128, false, false><<<(N + 127) / 128, 256, 0, stream>>>(
        h, nullptr, nullptr, W2a, nullptr, buf2, N);        // hA
    hipMemsetAsync(agg, 0, (size_t)N * HD * sizeof(float), stream);
    edge_k<<<(E + 127) / 128, 256, 0, stream>>>(
        ei, dist, buf2,
        m3w1 + (size_t)l * 3 * 128, m3b1 + (size_t)l * 128,
        Wf, ub,
        m2w2 + (size_t)l * 128 * 128, m2b2 + (size_t)l * 128,
        agg, E);
    gemm_node<256, true, true><<<(N + 127) / 128, 256, 0, stream>>>(
        agg, h, invd, m1w1 + (size_t)l * 256 * 128, m1b1 + (size_t)l * 128, buf2, N); // tmp
    gemm_node<128, true, false><<<(N + 127) / 128, 256, 0, stream>>>(
        buf2, nullptr, nullptr, m1w2 + (size_t)l * 128 * 128, m1b2 + (size_t)l * 128, h, N);
  }

  readout_k<<<(N + 3) / 4, 256, 0, stream>>>(h, l1w, l1b, l2w, l2b, batch, (float*)d_out, N);
}

// Round 2
// 2610.839 us; speedup vs baseline: 2.8394x; 2.8394x over previous
//
#include <hip/hip_runtime.h>

#define HD 128

// ---- degree count ----------------------------------------------------------
__global__ void count_k(const int* __restrict__ ei, int* __restrict__ cnt, int E) {
  int e = blockIdx.x * 256 + threadIdx.x;
  if (e < E) atomicAdd(&cnt[ei[E + e]], 1);
}

// ---- single-block exclusive scan: cnt -> start offsets (in place), invd ----
__global__ __launch_bounds__(1024) void scan_k(int* __restrict__ cnt,
                                               float* __restrict__ invd, int n) {
  __shared__ int wsum[16];
  const int tid = threadIdx.x;
  const int C = (n + 1023) >> 10;
  const int base = tid * C;
  int local = 0;
  for (int k = 0; k < C; ++k) { int i = base + k; if (i < n) local += cnt[i]; }
  int lane = tid & 63, wid = tid >> 6;
  int v = local;
#pragma unroll
  for (int off = 1; off < 64; off <<= 1) {
    int u = __shfl_up(v, off);
    if (lane >= off) v += u;
  }
  if (lane == 63) wsum[wid] = v;
  __syncthreads();
  if (tid == 0) {
    int s = 0;
    for (int w = 0; w < 16; ++w) { int t = wsum[w]; wsum[w] = s; s += t; }
  }
  __syncthreads();
  int running = v - local + wsum[wid];
  for (int k = 0; k < C; ++k) {
    int i = base + k;
    if (i < n) {
      int c = cnt[i];
      invd[i] = c > 0 ? 1.f / (float)c : 0.f;
      cnt[i] = running;
      running += c;
    }
  }
}

// ---- scatter into dst-sorted order: spk[p] = src | (dst<<16) ---------------
__global__ void scatter_k(const int* __restrict__ ei, int* __restrict__ cur,
                          unsigned int* __restrict__ spk, int E) {
  int e = blockIdx.x * 256 + threadIdx.x;
  if (e >= E) return;
  int s = ei[e], d = ei[E + e];
  int p = atomicAdd(&cur[d], 1);
  spk[p] = (unsigned int)s | ((unsigned int)d << 16);
}

// ---- weight folding (all layers, both folds, one launch) -------------------
// mode 0: Wf = w3_2 @ W2b ; ub = m2b1 + m3b2 @ W2b
// mode 1: Wm = w2_2 @ W1a ; bf = m2b2 @ W1a
__global__ void fold_all_k(const float* __restrict__ m3w2, const float* __restrict__ m2w1,
                           const float* __restrict__ m3b2, const float* __restrict__ m2b1,
                           const float* __restrict__ m2w2, const float* __restrict__ m1w1,
                           const float* __restrict__ m2b2,
                           float* __restrict__ Wf, float* __restrict__ ub,
                           float* __restrict__ Wm, float* __restrict__ bf) {
  const int k = blockIdx.x, l = blockIdx.y, mode = blockIdx.z, c = threadIdx.x;
  const float *A, *B, *bA, *badd;
  float *O, *ob;
  if (mode == 0) {
    A = m3w2 + (size_t)l * 128 * 128;
    B = m2w1 + (size_t)l * 256 * 128 + 128 * 128;  // W2b rows 128..255
    bA = m3b2 + (size_t)l * 128; badd = m2b1 + (size_t)l * 128;
    O = Wf + (size_t)l * 128 * 128; ob = ub + (size_t)l * 128;
  } else {
    A = m2w2 + (size_t)l * 128 * 128;
    B = m1w1 + (size_t)l * 256 * 128;              // W1a rows 0..127
    bA = m2b2 + (size_t)l * 128; badd = nullptr;
    O = Wm + (size_t)l * 128 * 128; ob = bf + (size_t)l * 128;
  }
  float s = 0.f;
  for (int r = 0; r < 128; ++r) s = fmaf(A[k * 128 + r], B[r * 128 + c], s);
  O[k * 128 + c] = s;
  if (k == 0) {
    float t = badd ? badd[c] : 0.f;
    for (int r = 0; r < 128; ++r) t = fmaf(bA[r], B[r * 128 + c], t);
    ob[c] = t;
  }
}

// ---- h1 = relu(x * w1 + b1) ------------------------------------------------
__global__ void node_init_k(const float* __restrict__ x, const float* __restrict__ w1,
                            const float* __restrict__ b1, float* __restrict__ h1, int n) {
  int i = blockIdx.x * 2 + (threadIdx.x >> 7);
  int j = threadIdx.x & 127;
  if (i >= n) return;
  float v = fmaf(x[i], w1[j], b1[j]);
  h1[(size_t)i * HD + j] = v > 0.f ? v : 0.f;
}

// ---- node GEMM: out = act( [sc.*in0 | in1] @ [W0;W1] + bias + [sc>0]*bias2 )
template<int K, bool RELU, bool SCALE0, bool BIAS2>
__global__ __launch_bounds__(256) void gemm_node(
    const float* __restrict__ in0, const float* __restrict__ in1,
    const float* __restrict__ sc,
    const float* __restrict__ W0, const float* __restrict__ W1,
    const float* __restrict__ bias, const float* __restrict__ bias2,
    float* __restrict__ out, int M)
{
  __shared__ float A[16][132];
  __shared__ float B[16][132];
  const int tid = threadIdx.x;
  const int ty = tid >> 4, tx = tid & 15;
  const int m0 = blockIdx.x * 128;

  float acc[8][8];
#pragma unroll
  for (int i = 0; i < 8; ++i)
#pragma unroll
    for (int j = 0; j < 8; ++j) acc[i][j] = 0.f;

  for (int kc = 0; kc < K; kc += 16) {
    __syncthreads();
    { // stage A chunk (transposed to [k][m])
      int m = tid >> 1, kh = (tid & 1) * 8;
      int gm = m0 + m, kk = kc + kh;
      float4 v0 = {0,0,0,0}, v1 = {0,0,0,0};
      if (gm < M) {
        const float* base = (K == 256 && kk >= 128) ? (in1 + (size_t)gm * HD + (kk - 128))
                                                    : (in0 + (size_t)gm * HD + kk);
        v0 = *(const float4*)base;
        v1 = *(const float4*)(base + 4);
        if (SCALE0 && kk < 128) {
          float s = sc[gm];
          v0.x *= s; v0.y *= s; v0.z *= s; v0.w *= s;
          v1.x *= s; v1.y *= s; v1.z *= s; v1.w *= s;
        }
      }
      A[kh+0][m] = v0.x; A[kh+1][m] = v0.y; A[kh+2][m] = v0.z; A[kh+3][m] = v0.w;
      A[kh+4][m] = v1.x; A[kh+5][m] = v1.y; A[kh+6][m] = v1.z; A[kh+7][m] = v1.w;
    }
    { // stage B chunk
      int k = tid >> 4, c = (tid & 15) * 8;
      const float* Wsrc = (K == 256 && kc >= 128) ? (W1 + (size_t)(kc - 128 + k) * HD)
                                                  : (W0 + (size_t)(kc + k) * HD);
      *(float4*)&B[k][c]   = *(const float4*)&Wsrc[c];
      *(float4*)&B[k][c+4] = *(const float4*)&Wsrc[c + 4];
    }
    __syncthreads();
#pragma unroll
    for (int kk = 0; kk < 16; ++kk) {
      float4 a0 = *(const float4*)&A[kk][ty*8];
      float4 a1 = *(const float4*)&A[kk][ty*8+4];
      float4 b0 = *(const float4*)&B[kk][tx*8];
      float4 b1 = *(const float4*)&B[kk][tx*8+4];
      float av[8] = {a0.x,a0.y,a0.z,a0.w,a1.x,a1.y,a1.z,a1.w};
      float bv[8] = {b0.x,b0.y,b0.z,b0.w,b1.x,b1.y,b1.z,b1.w};
#pragma unroll
      for (int i = 0; i < 8; ++i)
#pragma unroll
        for (int j = 0; j < 8; ++j) acc[i][j] = fmaf(av[i], bv[j], acc[i][j]);
    }
  }

  float bv[8];
  if (bias) {
    float4 b0 = *(const float4*)&bias[tx*8];
    float4 b1 = *(const float4*)&bias[tx*8+4];
    bv[0]=b0.x; bv[1]=b0.y; bv[2]=b0.z; bv[3]=b0.w;
    bv[4]=b1.x; bv[5]=b1.y; bv[6]=b1.z; bv[7]=b1.w;
  } else {
#pragma unroll
    for (int j = 0; j < 8; ++j) bv[j] = 0.f;
  }
  float b2v[8] = {0,0,0,0,0,0,0,0};
  if (BIAS2) {
    float4 c0 = *(const float4*)&bias2[tx*8];
    float4 c1 = *(const float4*)&bias2[tx*8+4];
    b2v[0]=c0.x; b2v[1]=c0.y; b2v[2]=c0.z; b2v[3]=c0.w;
    b2v[4]=c1.x; b2v[5]=c1.y; b2v[6]=c1.z; b2v[7]=c1.w;
  }
#pragma unroll
  for (int i = 0; i < 8; ++i) {
    int gm = m0 + ty*8 + i;
    if (gm < M) {
      float m2 = 0.f;
      if (BIAS2) m2 = (sc[gm] > 0.f) ? 1.f : 0.f;
      float o[8];
#pragma unroll
      for (int j = 0; j < 8; ++j) {
        float v = acc[i][j] + bv[j] + (BIAS2 ? m2 * b2v[j] : 0.f);
        o[j] = (RELU && v < 0.f) ? 0.f : v;
      }
      float4 s0 = {o[0],o[1],o[2],o[3]}, s1 = {o[4],o[5],o[6],o[7]};
      *(float4*)&out[(size_t)gm * HD + tx*8]     = s0;
      *(float4*)&out[(size_t)gm * HD + tx*8 + 4] = s1;
    }
  }
}

// ---- fused edge kernel on dst-sorted edges ---------------------------------
// P_e = relu(t_e @ Wf + hA[src_e] + ub); Pagg[dst] += P_e (segmented flush)
__global__ __launch_bounds__(256, 2) void edge_k(
    const unsigned int* __restrict__ spk, const float* __restrict__ pos,
    const float* __restrict__ hA,
    const float* __restrict__ w31, const float* __restrict__ b31,
    const float* __restrict__ Wf, const float* __restrict__ ub,
    float* __restrict__ Pagg, int E)
{
  __shared__ float T[128][132];   // t as [k][e]
  __shared__ float WC[16][132];   // Wf K-chunk
  __shared__ int SS[128];
  __shared__ int SD[128];
  const int tid = threadIdx.x;
  const int ty = tid >> 4, tx = tid & 15;
  const int e0 = blockIdx.x * 128;

  // stage 1: unpack edge, dist on the fly, t = relu(dist@w31 + b31)
  {
    int el = tid & 127;
    int p = e0 + el;
    int s = 0, d = -1;
    float d0 = 0.f, d1 = 0.f, d2 = 0.f;
    if (p < E) {
      unsigned int pk = spk[p];
      s = (int)(pk & 0xffffu);
      d = (int)(pk >> 16);
      d0 = pos[(size_t)s*3+0] - pos[(size_t)d*3+0];
      d1 = pos[(size_t)s*3+1] - pos[(size_t)d*3+1];
      d2 = pos[(size_t)s*3+2] - pos[(size_t)d*3+2];
    }
    if (tid < 128) { SS[tid] = s; SD[tid] = d; }
    int k0 = (tid >> 7) * 64;
#pragma unroll 4
    for (int k = k0; k < k0 + 64; ++k) {
      float v = fmaf(d0, w31[k], fmaf(d1, w31[128+k], fmaf(d2, w31[256+k], b31[k])));
      T[k][el] = v > 0.f ? v : 0.f;
    }
  }
  __syncthreads();

  // prefetch hA rows for this thread's 8 edges (hidden under the GEMM)
  float4 hv0[8], hv1[8];
#pragma unroll
  for (int i = 0; i < 8; ++i) {
    int s = SS[ty*8 + i];
    const float* hr = hA + (size_t)s * HD + tx*8;
    hv0[i] = *(const float4*)hr;
    hv1[i] = *(const float4*)(hr + 4);
  }

  float acc[8][8];
#pragma unroll
  for (int i = 0; i < 8; ++i)
#pragma unroll
    for (int j = 0; j < 8; ++j) acc[i][j] = 0.f;

  // u = t @ Wfold
  for (int kc = 0; kc < 128; kc += 16) {
    __syncthreads();
    {
      int lk = tid >> 4, lc = (tid & 15) * 8;
      *(float4*)&WC[lk][lc]   = *(const float4*)&Wf[(size_t)(kc+lk)*HD + lc];
      *(float4*)&WC[lk][lc+4] = *(const float4*)&Wf[(size_t)(kc+lk)*HD + lc + 4];
    }
    __syncthreads();
#pragma unroll
    for (int kk = 0; kk < 16; ++kk) {
      float4 a0 = *(const float4*)&T[kc+kk][ty*8];
      float4 a1 = *(const float4*)&T[kc+kk][ty*8+4];
      float4 b0 = *(const float4*)&WC[kk][tx*8];
      float4 b1 = *(const float4*)&WC[kk][tx*8+4];
      float av[8] = {a0.x,a0.y,a0.z,a0.w,a1.x,a1.y,a1.z,a1.w};
      float bv[8] = {b0.x,b0.y,b0.z,b0.w,b1.x,b1.y,b1.z,b1.w};
#pragma unroll
      for (int i = 0; i < 8; ++i)
#pragma unroll
        for (int j = 0; j < 8; ++j) acc[i][j] = fmaf(av[i], bv[j], acc[i][j]);
    }
  }

  // epilogue: P = relu(u + hA[src] + ub), segmented reduce by dst, flush
  {
    float4 u0 = *(const float4*)&ub[tx*8];
    float4 u1 = *(const float4*)&ub[tx*8+4];
    float ubv[8] = {u0.x,u0.y,u0.z,u0.w,u1.x,u1.y,u1.z,u1.w};
    float sum[8] = {0,0,0,0,0,0,0,0};
    int dcur = SD[ty*8];
#pragma unroll
    for (int i = 0; i < 8; ++i) {
      int d = SD[ty*8 + i];
      if (d != dcur) {
        if (dcur >= 0) {
          float* dstp = &Pagg[(size_t)dcur * HD + tx*8];
#pragma unroll
          for (int j = 0; j < 8; ++j) atomicAdd(&dstp[j], sum[j]);
        }
#pragma unroll
        for (int j = 0; j < 8; ++j) sum[j] = 0.f;
        dcur = d;
      }
      if (d >= 0) {
        float hvv[8] = {hv0[i].x,hv0[i].y,hv0[i].z,hv0[i].w,
                        hv1[i].x,hv1[i].y,hv1[i].z,hv1[i].w};
#pragma unroll
        for (int j = 0; j < 8; ++j) {
          float v = acc[i][j] + hvv[j] + ubv[j];
          sum[j] += v > 0.f ? v : 0.f;
        }
      }
    }
    if (dcur >= 0) {
      float* dstp = &Pagg[(size_t)dcur * HD + tx*8];
#pragma unroll
      for (int j = 0; j < 8; ++j) atomicAdd(&dstp[j], sum[j]);
    }
  }
}

// ---- readout ---------------------------------------------------------------
__global__ __launch_bounds__(256) void readout_k(
    const float* __restrict__ h, const float* __restrict__ l1w, const float* __restrict__ l1b,
    const float* __restrict__ l2w, const float* __restrict__ l2b,
    const int* __restrict__ batch, float* __restrict__ out, int n)
{
  int node = blockIdx.x * 4 + (threadIdx.x >> 6);
  int lane = threadIdx.x & 63;
  if (node >= n) return;
  const float* hr = h + (size_t)node * HD;
  float z = l1b[lane];
  for (int k = 0; k < 128; ++k) z = fmaf(hr[k], l1w[k*64 + lane], z);
  float t = z > 0.f ? z * l2w[lane] : 0.f;
#pragma unroll
  for (int off = 32; off > 0; off >>= 1) t += __shfl_down(t, off);
  if (lane == 0) atomicAdd(&out[batch[node]], t + l2b[0]);
}

extern "C" void kernel_launch(void* const* d_in, const int* in_sizes, int n_in,
                              void* d_out, int out_size, void* d_ws, size_t ws_size,
                              hipStream_t stream) {
  const float* x     = (const float*)d_in[0];
  const float* pos   = (const float*)d_in[1];
  const int*   ei    = (const int*)d_in[2];
  const int*   batch = (const int*)d_in[3];
  const float* nw1   = (const float*)d_in[4];
  const float* nb1   = (const float*)d_in[5];
  const float* nw2   = (const float*)d_in[6];
  const float* nb2   = (const float*)d_in[7];
  const float* m1w1  = (const float*)d_in[8];
  const float* m1b1  = (const float*)d_in[9];
  const float* m1w2  = (const float*)d_in[10];
  const float* m1b2  = (const float*)d_in[11];
  const float* m2w1  = (const float*)d_in[12];
  const float* m2b1  = (const float*)d_in[13];
  const float* m2w2  = (const float*)d_in[14];
  const float* m2b2  = (const float*)d_in[15];
  const float* m3w1  = (const float*)d_in[16];
  const float* m3b1  = (const float*)d_in[17];
  const float* m3w2  = (const float*)d_in[18];
  const float* m3b2  = (const float*)d_in[19];
  const float* l1w   = (const float*)d_in[20];
  const float* l1b   = (const float*)d_in[21];
  const float* l2w   = (const float*)d_in[22];
  const float* l2b   = (const float*)d_in[23];

  const int N = in_sizes[0];
  const int E = in_sizes[2] / 2;
  const int L = in_sizes[8] / (256 * 128);

  float* h    = (float*)d_ws;                     // [N,128]
  float* buf2 = h    + (size_t)N * HD;            // hA / tmp      [N,128]
  float* Pagg = buf2 + (size_t)N * HD;            // [N,128]
  unsigned int* spk = (unsigned int*)(Pagg + (size_t)N * HD);  // [E]
  int*   cnt  = (int*)(spk + E);                  // [N]
  float* invd = (float*)(cnt + N);                // [N]
  float* Wf   = invd + N;                         // [L,128,128]
  float* ub   = Wf + (size_t)L * 128 * 128;       // [L,128]
  float* Wm   = ub + (size_t)L * 128;             // [L,128,128]
  float* bf   = Wm + (size_t)L * 128 * 128;       // [L,128]

  hipMemsetAsync(cnt, 0, (size_t)N * sizeof(int), stream);
  hipMemsetAsync(d_out, 0, (size_t)out_size * sizeof(float), stream);

  count_k<<<(E + 255) / 256, 256, 0, stream>>>(ei, cnt, E);
  scan_k<<<1, 1024, 0, stream>>>(cnt, invd, N);
  scatter_k<<<(E + 255) / 256, 256, 0, stream>>>(ei, cnt, spk, E);
  fold_all_k<<<dim3(128, L, 2), 128, 0, stream>>>(m3w2, m2w1, m3b2, m2b1,
                                                  m2w2, m1w1, m2b2, Wf, ub, Wm, bf);

  node_init_k<<<(N + 1) / 2, 256, 0, stream>>>(x, nw1, nb1, buf2, N);
  gemm_node<128, false, false, false><<<(N + 127) / 128, 256, 0, stream>>>(
      buf2, nullptr, nullptr, nw2, nullptr, nb2, nullptr, h, N);

  for (int l = 0; l < L; ++l) {
    const float* W2a = m2w1 + (size_t)l * 256 * 128;   // rows 0..127 (h[src] part)
    const float* W1b = m1w1 + (size_t)l * 256 * 128 + 128 * 128; // rows 128..255 (h part)
    // hA = h @ W2a
    gemm_node<128, false, false, false><<<(N + 127) / 128, 256, 0, stream>>>(
        h, nullptr, nullptr, W2a, nullptr, nullptr, nullptr, buf2, N);
    hipMemsetAsync(Pagg, 0, (size_t)N * HD * sizeof(float), stream);
    edge_k<<<(E + 127) / 128, 256, 0, stream>>>(
        spk, pos, buf2,
        m3w1 + (size_t)l * 3 * 128, m3b1 + (size_t)l * 128,
        Wf + (size_t)l * 128 * 128, ub + (size_t)l * 128,
        Pagg, E);
    // tmp = relu((Pagg*invd)@Wm + [deg>0]*bf + h@W1b + m1b1)
    gemm_node<256, true, true, true><<<(N + 127) / 128, 256, 0, stream>>>(
        Pagg, h, invd, Wm + (size_t)l * 128 * 128, W1b,
        m1b1 + (size_t)l * 128, bf + (size_t)l * 128, buf2, N);
    // h = relu(tmp @ m1w2 + m1b2)
    gemm_node<128, true, false, false><<<(N + 127) / 128, 256, 0, stream>>>(
        buf2, nullptr, nullptr, m1w2 + (size_t)l * 128 * 128, nullptr,
        m1b2 + (size_t)l * 128, nullptr, h, N);
  }

  readout_k<<<(N + 3) / 4, 256, 0, stream>>>(h, l1w, l1b, l2w, l2b, batch, (float*)d_out, N);
}

// Round 3
// 2108.387 us; speedup vs baseline: 3.5161x; 1.2383x over previous
//
#include <hip/hip_runtime.h>

#define HD 128

typedef __attribute__((ext_vector_type(8))) short bf16x8;
typedef __attribute__((ext_vector_type(4))) float f32x4;

// ---- bf16 helpers ----------------------------------------------------------
__device__ __forceinline__ unsigned rne16(float x) {
  unsigned u = __builtin_bit_cast(unsigned, x);
  return (u + 0x7fffu + ((u >> 16) & 1u)) >> 16;
}
__device__ __forceinline__ unsigned bfpack(float a, float b) {
  return rne16(a) | (rne16(b) << 16);
}
__device__ __forceinline__ float blo(unsigned u) { return __builtin_bit_cast(float, u << 16); }
__device__ __forceinline__ float bhi(unsigned u) { return __builtin_bit_cast(float, u & 0xffff0000u); }

// ---- degree count ----------------------------------------------------------
__global__ void count_k(const int* __restrict__ ei, int* __restrict__ cnt, int E) {
  int e = blockIdx.x * 256 + threadIdx.x;
  if (e < E) atomicAdd(&cnt[ei[E + e]], 1);
}

// ---- single-block exclusive scan -------------------------------------------
__global__ __launch_bounds__(1024) void scan_k(int* __restrict__ cnt,
                                               float* __restrict__ invd, int n) {
  __shared__ int wsum[16];
  const int tid = threadIdx.x;
  const int C = (n + 1023) >> 10;
  const int base = tid * C;
  int local = 0;
  for (int k = 0; k < C; ++k) { int i = base + k; if (i < n) local += cnt[i]; }
  int lane = tid & 63, wid = tid >> 6;
  int v = local;
#pragma unroll
  for (int off = 1; off < 64; off <<= 1) {
    int u = __shfl_up(v, off);
    if (lane >= off) v += u;
  }
  if (lane == 63) wsum[wid] = v;
  __syncthreads();
  if (tid == 0) {
    int s = 0;
    for (int w = 0; w < 16; ++w) { int t = wsum[w]; wsum[w] = s; s += t; }
  }
  __syncthreads();
  int running = v - local + wsum[wid];
  for (int k = 0; k < C; ++k) {
    int i = base + k;
    if (i < n) {
      int c = cnt[i];
      invd[i] = c > 0 ? 1.f / (float)c : 0.f;
      cnt[i] = running;
      running += c;
    }
  }
}

// ---- scatter into dst-sorted order: spk[p] = src | (dst<<16) ---------------
__global__ void scatter_k(const int* __restrict__ ei, int* __restrict__ cur,
                          unsigned int* __restrict__ spk, int E) {
  int e = blockIdx.x * 256 + threadIdx.x;
  if (e >= E) return;
  int s = ei[e], d = ei[E + e];
  int p = atomicAdd(&cur[d], 1);
  spk[p] = (unsigned int)s | ((unsigned int)d << 16);
}

// ---- weight folding --------------------------------------------------------
__global__ void fold_all_k(const float* __restrict__ m3w2, const float* __restrict__ m2w1,
                           const float* __restrict__ m3b2, const float* __restrict__ m2b1,
                           const float* __restrict__ m2w2, const float* __restrict__ m1w1,
                           const float* __restrict__ m2b2,
                           float* __restrict__ Wf, float* __restrict__ ub,
                           float* __restrict__ Wm, float* __restrict__ bf) {
  const int k = blockIdx.x, l = blockIdx.y, mode = blockIdx.z, c = threadIdx.x;
  const float *A, *B, *bA, *badd;
  float *O, *ob;
  if (mode == 0) {
    A = m3w2 + (size_t)l * 128 * 128;
    B = m2w1 + (size_t)l * 256 * 128 + 128 * 128;
    bA = m3b2 + (size_t)l * 128; badd = m2b1 + (size_t)l * 128;
    O = Wf + (size_t)l * 128 * 128; ob = ub + (size_t)l * 128;
  } else {
    A = m2w2 + (size_t)l * 128 * 128;
    B = m1w1 + (size_t)l * 256 * 128;
    bA = m2b2 + (size_t)l * 128; badd = nullptr;
    O = Wm + (size_t)l * 128 * 128; ob = bf + (size_t)l * 128;
  }
  float s = 0.f;
  for (int r = 0; r < 128; ++r) s = fmaf(A[k * 128 + r], B[r * 128 + c], s);
  O[k * 128 + c] = s;
  if (k == 0) {
    float t = badd ? badd[c] : 0.f;
    for (int r = 0; r < 128; ++r) t = fmaf(bA[r], B[r * 128 + c], t);
    ob[c] = t;
  }
}

// ---- pack Wf into bf16 MFMA B-fragment order -------------------------------
// Wpk[l][flat], flat = ((kt*8+ct)*64+lane)*8+e ; value = Wf[kt*32+(lane>>4)*8+e][ct*16+(lane&15)]
__global__ void pack_k(const float* __restrict__ Wf, unsigned short* __restrict__ Wpk) {
  int l = blockIdx.y;
  int flat = blockIdx.x * 256 + threadIdx.x;     // 0..16383
  int e = flat & 7, l6 = (flat >> 3) & 63, ct = (flat >> 9) & 7, kt = flat >> 12;
  int row = kt * 32 + ((l6 >> 4) << 3) + e;
  int col = ct * 16 + (l6 & 15);
  Wpk[(size_t)l * 16384 + flat] =
      (unsigned short)rne16(Wf[(size_t)l * 16384 + row * 128 + col]);
}

// ---- h1 = relu(x * w1 + b1) ------------------------------------------------
__global__ void node_init_k(const float* __restrict__ x, const float* __restrict__ w1,
                            const float* __restrict__ b1, float* __restrict__ h1, int n) {
  int i = blockIdx.x * 2 + (threadIdx.x >> 7);
  int j = threadIdx.x & 127;
  if (i >= n) return;
  float v = fmaf(x[i], w1[j], b1[j]);
  h1[(size_t)i * HD + j] = v > 0.f ? v : 0.f;
}

// ---- node GEMM (fp32 VALU) -------------------------------------------------
template<int K, bool RELU, bool SCALE0, bool BIAS2, bool OUTBF16>
__global__ __launch_bounds__(256) void gemm_node(
    const float* __restrict__ in0, const float* __restrict__ in1,
    const float* __restrict__ sc,
    const float* __restrict__ W0, const float* __restrict__ W1,
    const float* __restrict__ bias, const float* __restrict__ bias2,
    float* __restrict__ out, int M)
{
  __shared__ float A[16][132];
  __shared__ float B[16][132];
  const int tid = threadIdx.x;
  const int ty = tid >> 4, tx = tid & 15;
  const int m0 = blockIdx.x * 128;

  float acc[8][8];
#pragma unroll
  for (int i = 0; i < 8; ++i)
#pragma unroll
    for (int j = 0; j < 8; ++j) acc[i][j] = 0.f;

  for (int kc = 0; kc < K; kc += 16) {
    __syncthreads();
    {
      int m = tid >> 1, kh = (tid & 1) * 8;
      int gm = m0 + m, kk = kc + kh;
      float4 v0 = {0,0,0,0}, v1 = {0,0,0,0};
      if (gm < M) {
        const float* base = (K == 256 && kk >= 128) ? (in1 + (size_t)gm * HD + (kk - 128))
                                                    : (in0 + (size_t)gm * HD + kk);
        v0 = *(const float4*)base;
        v1 = *(const float4*)(base + 4);
        if (SCALE0 && kk < 128) {
          float s = sc[gm];
          v0.x *= s; v0.y *= s; v0.z *= s; v0.w *= s;
          v1.x *= s; v1.y *= s; v1.z *= s; v1.w *= s;
        }
      }
      A[kh+0][m] = v0.x; A[kh+1][m] = v0.y; A[kh+2][m] = v0.z; A[kh+3][m] = v0.w;
      A[kh+4][m] = v1.x; A[kh+5][m] = v1.y; A[kh+6][m] = v1.z; A[kh+7][m] = v1.w;
    }
    {
      int k = tid >> 4, c = (tid & 15) * 8;
      const float* Wsrc = (K == 256 && kc >= 128) ? (W1 + (size_t)(kc - 128 + k) * HD)
                                                  : (W0 + (size_t)(kc + k) * HD);
      *(float4*)&B[k][c]   = *(const float4*)&Wsrc[c];
      *(float4*)&B[k][c+4] = *(const float4*)&Wsrc[c + 4];
    }
    __syncthreads();
#pragma unroll
    for (int kk = 0; kk < 16; ++kk) {
      float4 a0 = *(const float4*)&A[kk][ty*8];
      float4 a1 = *(const float4*)&A[kk][ty*8+4];
      float4 b0 = *(const float4*)&B[kk][tx*8];
      float4 b1 = *(const float4*)&B[kk][tx*8+4];
      float av[8] = {a0.x,a0.y,a0.z,a0.w,a1.x,a1.y,a1.z,a1.w};
      float bv[8] = {b0.x,b0.y,b0.z,b0.w,b1.x,b1.y,b1.z,b1.w};
#pragma unroll
      for (int i = 0; i < 8; ++i)
#pragma unroll
        for (int j = 0; j < 8; ++j) acc[i][j] = fmaf(av[i], bv[j], acc[i][j]);
    }
  }

  float bv[8];
  if (bias) {
    float4 b0 = *(const float4*)&bias[tx*8];
    float4 b1 = *(const float4*)&bias[tx*8+4];
    bv[0]=b0.x; bv[1]=b0.y; bv[2]=b0.z; bv[3]=b0.w;
    bv[4]=b1.x; bv[5]=b1.y; bv[6]=b1.z; bv[7]=b1.w;
  } else {
#pragma unroll
    for (int j = 0; j < 8; ++j) bv[j] = 0.f;
  }
  float b2v[8] = {0,0,0,0,0,0,0,0};
  if (BIAS2) {
    float4 c0 = *(const float4*)&bias2[tx*8];
    float4 c1 = *(const float4*)&bias2[tx*8+4];
    b2v[0]=c0.x; b2v[1]=c0.y; b2v[2]=c0.z; b2v[3]=c0.w;
    b2v[4]=c1.x; b2v[5]=c1.y; b2v[6]=c1.z; b2v[7]=c1.w;
  }
#pragma unroll
  for (int i = 0; i < 8; ++i) {
    int gm = m0 + ty*8 + i;
    if (gm < M) {
      float m2 = 0.f;
      if (BIAS2) m2 = (sc[gm] > 0.f) ? 1.f : 0.f;
      float o[8];
#pragma unroll
      for (int j = 0; j < 8; ++j) {
        float v = acc[i][j] + bv[j] + (BIAS2 ? m2 * b2v[j] : 0.f);
        o[j] = (RELU && v < 0.f) ? 0.f : v;
      }
      if (OUTBF16) {
        unsigned short* ob = (unsigned short*)out;
        uint4 pk;
        pk.x = bfpack(o[0], o[1]); pk.y = bfpack(o[2], o[3]);
        pk.z = bfpack(o[4], o[5]); pk.w = bfpack(o[6], o[7]);
        *(uint4*)&ob[(size_t)gm * HD + tx*8] = pk;
      } else {
        float4 s0 = {o[0],o[1],o[2],o[3]}, s1 = {o[4],o[5],o[6],o[7]};
        *(float4*)&out[(size_t)gm * HD + tx*8]     = s0;
        *(float4*)&out[(size_t)gm * HD + tx*8 + 4] = s1;
      }
    }
  }
}

// ---- fused edge kernel: MFMA bf16 GEMM + segmented atomic reduce -----------
__global__ __launch_bounds__(256, 4) void edge_k(
    const unsigned int* __restrict__ spk, const float* __restrict__ pos,
    const unsigned short* __restrict__ hAb,
    const float* __restrict__ w31, const float* __restrict__ b31,
    const unsigned short* __restrict__ Wpk, const float* __restrict__ ub,
    float* __restrict__ Pagg, int E, int nwg)
{
  __shared__ __align__(16) unsigned short Tw[128 * 128];  // t (swizzled) then u
  __shared__ int SS[128];
  __shared__ int SD[128];
  const int tid = threadIdx.x;

  // XCD-bijective block swizzle: consecutive work chunks stay on one XCD
  int b = blockIdx.x;
  int q = nwg >> 3, r = nwg & 7;
  int xcd = b & 7, sub = b >> 3;
  int wg = (xcd < r ? xcd * (q + 1) : r * (q + 1) + (xcd - r) * q) + sub;
  const int e0 = wg * 128;

  // ---- stage 1: t = relu(dist @ w31 + b31) -> bf16 LDS (A-fragment layout) --
  {
    int el = tid & 127;
    int p = e0 + el;
    int s = 0, d = -1;
    float d0 = 0.f, d1 = 0.f, d2 = 0.f;
    if (p < E) {
      unsigned int pk = spk[p];
      s = (int)(pk & 0xffffu);
      d = (int)(pk >> 16);
      d0 = pos[(size_t)s*3+0] - pos[(size_t)d*3+0];
      d1 = pos[(size_t)s*3+1] - pos[(size_t)d*3+1];
      d2 = pos[(size_t)s*3+2] - pos[(size_t)d*3+2];
    }
    if (tid < 128) { SS[tid] = s; SD[tid] = d; }
    int k0 = (tid >> 7) * 64;
    int swz = el & 7;
#pragma unroll
    for (int g = 0; g < 8; ++g) {
      int kb = (k0 >> 3) + g;       // 16B-block index 0..15
      float v[8];
#pragma unroll
      for (int j = 0; j < 8; ++j) {
        int k = k0 + g*8 + j;
        float t = fmaf(d0, w31[k], fmaf(d1, w31[128+k], fmaf(d2, w31[256+k], b31[k])));
        v[j] = t > 0.f ? t : 0.f;
      }
      uint4 w;
      w.x = bfpack(v[0], v[1]); w.y = bfpack(v[2], v[3]);
      w.z = bfpack(v[4], v[5]); w.w = bfpack(v[6], v[7]);
      *(uint4*)&Tw[el * 128 + ((kb ^ swz) << 3)] = w;
    }
  }
  __syncthreads();

  // ---- stage 2: u = t @ Wf via MFMA ----------------------------------------
  const int lane = tid & 63, w4 = tid >> 6;
  const int lrow = lane & 15, lk = lane >> 4;
  f32x4 acc[2][8];
#pragma unroll
  for (int rt = 0; rt < 2; ++rt)
#pragma unroll
    for (int ct = 0; ct < 8; ++ct) acc[rt][ct] = (f32x4){0.f, 0.f, 0.f, 0.f};

#pragma unroll
  for (int kt = 0; kt < 4; ++kt) {
    bf16x8 a[2];
#pragma unroll
    for (int rt = 0; rt < 2; ++rt) {
      int e = w4*32 + rt*16 + lrow;
      int kb = kt*4 + lk;
      a[rt] = *(const bf16x8*)&Tw[e * 128 + ((kb ^ (e & 7)) << 3)];
    }
#pragma unroll
    for (int cg = 0; cg < 2; ++cg) {
      bf16x8 bq[4];
#pragma unroll
      for (int c4 = 0; c4 < 4; ++c4)
        bq[c4] = *(const bf16x8*)&Wpk[(size_t)(((kt*8 + cg*4 + c4) * 64) + lane) * 8];
#pragma unroll
      for (int rt = 0; rt < 2; ++rt)
#pragma unroll
        for (int c4 = 0; c4 < 4; ++c4)
          acc[rt][cg*4 + c4] = __builtin_amdgcn_mfma_f32_16x16x32_bf16(
              a[rt], bq[c4], acc[rt][cg*4 + c4], 0, 0, 0);
    }
  }
  __syncthreads();

  // ---- write u (bf16) into Tw as [e][c], unswizzled ------------------------
#pragma unroll
  for (int rt = 0; rt < 2; ++rt) {
    int ebase = w4*32 + rt*16 + lk*4;
#pragma unroll
    for (int ct = 0; ct < 8; ++ct) {
      int c = ct*16 + lrow;
      Tw[(ebase+0)*128 + c] = (unsigned short)rne16(acc[rt][ct][0]);
      Tw[(ebase+1)*128 + c] = (unsigned short)rne16(acc[rt][ct][1]);
      Tw[(ebase+2)*128 + c] = (unsigned short)rne16(acc[rt][ct][2]);
      Tw[(ebase+3)*128 + c] = (unsigned short)rne16(acc[rt][ct][3]);
    }
  }
  __syncthreads();

  // ---- epilogue: P = relu(u + hA[src] + ub), segmented reduce, atomics -----
  {
    const int ty = tid >> 4, tx = tid & 15;
    uint4 hv[8];
#pragma unroll
    for (int i = 0; i < 8; ++i) {
      int s = SS[ty*8 + i];
      hv[i] = *(const uint4*)&hAb[(size_t)s * HD + tx*8];
    }
    float4 u0 = *(const float4*)&ub[tx*8];
    float4 u1 = *(const float4*)&ub[tx*8+4];
    float ubv[8] = {u0.x,u0.y,u0.z,u0.w,u1.x,u1.y,u1.z,u1.w};
    float sum[8] = {0,0,0,0,0,0,0,0};
    int dcur = SD[ty*8];
#pragma unroll
    for (int i = 0; i < 8; ++i) {
      int d = SD[ty*8 + i];
      if (d != dcur) {
        if (dcur >= 0) {
          float* dstp = &Pagg[(size_t)dcur * HD + tx*8];
#pragma unroll
          for (int j = 0; j < 8; ++j) atomicAdd(&dstp[j], sum[j]);
        }
#pragma unroll
        for (int j = 0; j < 8; ++j) sum[j] = 0.f;
        dcur = d;
      }
      if (d >= 0) {
        uint4 uv = *(const uint4*)&Tw[(ty*8 + i) * 128 + tx*8];
        float uvv[8] = {blo(uv.x),bhi(uv.x),blo(uv.y),bhi(uv.y),
                        blo(uv.z),bhi(uv.z),blo(uv.w),bhi(uv.w)};
        float hvv[8] = {blo(hv[i].x),bhi(hv[i].x),blo(hv[i].y),bhi(hv[i].y),
                        blo(hv[i].z),bhi(hv[i].z),blo(hv[i].w),bhi(hv[i].w)};
#pragma unroll
        for (int j = 0; j < 8; ++j) {
          float v = uvv[j] + hvv[j] + ubv[j];
          sum[j] += v > 0.f ? v : 0.f;
        }
      }
    }
    if (dcur >= 0) {
      float* dstp = &Pagg[(size_t)dcur * HD + tx*8];
#pragma unroll
      for (int j = 0; j < 8; ++j) atomicAdd(&dstp[j], sum[j]);
    }
  }
}

// ---- readout ---------------------------------------------------------------
__global__ __launch_bounds__(256) void readout_k(
    const float* __restrict__ h, const float* __restrict__ l1w, const float* __restrict__ l1b,
    const float* __restrict__ l2w, const float* __restrict__ l2b,
    const int* __restrict__ batch, float* __restrict__ out, int n)
{
  int node = blockIdx.x * 4 + (threadIdx.x >> 6);
  int lane = threadIdx.x & 63;
  if (node >= n) return;
  const float* hr = h + (size_t)node * HD;
  float z = l1b[lane];
  for (int k = 0; k < 128; ++k) z = fmaf(hr[k], l1w[k*64 + lane], z);
  float t = z > 0.f ? z * l2w[lane] : 0.f;
#pragma unroll
  for (int off = 32; off > 0; off >>= 1) t += __shfl_down(t, off);
  if (lane == 0) atomicAdd(&out[batch[node]], t + l2b[0]);
}

extern "C" void kernel_launch(void* const* d_in, const int* in_sizes, int n_in,
                              void* d_out, int out_size, void* d_ws, size_t ws_size,
                              hipStream_t stream) {
  const float* x     = (const float*)d_in[0];
  const float* pos   = (const float*)d_in[1];
  const int*   ei    = (const int*)d_in[2];
  const int*   batch = (const int*)d_in[3];
  const float* nw1   = (const float*)d_in[4];
  const float* nb1   = (const float*)d_in[5];
  const float* nw2   = (const float*)d_in[6];
  const float* nb2   = (const float*)d_in[7];
  const float* m1w1  = (const float*)d_in[8];
  const float* m1b1  = (const float*)d_in[9];
  const float* m1w2  = (const float*)d_in[10];
  const float* m1b2  = (const float*)d_in[11];
  const float* m2w1  = (const float*)d_in[12];
  const float* m2b1  = (const float*)d_in[13];
  const float* m2w2  = (const float*)d_in[14];
  const float* m2b2  = (const float*)d_in[15];
  const float* m3w1  = (const float*)d_in[16];
  const float* m3b1  = (const float*)d_in[17];
  const float* m3w2  = (const float*)d_in[18];
  const float* m3b2  = (const float*)d_in[19];
  const float* l1w   = (const float*)d_in[20];
  const float* l1b   = (const float*)d_in[21];
  const float* l2w   = (const float*)d_in[22];
  const float* l2b   = (const float*)d_in[23];

  const int N = in_sizes[0];
  const int E = in_sizes[2] / 2;
  const int L = in_sizes[8] / (256 * 128);

  float* h    = (float*)d_ws;                     // [N,128]
  float* buf2 = h    + (size_t)N * HD;            // tmp [N,128]
  float* Pagg = buf2 + (size_t)N * HD;            // [N,128]
  unsigned int* spk = (unsigned int*)(Pagg + (size_t)N * HD);  // [E]
  int*   cnt  = (int*)(spk + E);                  // [N]
  float* invd = (float*)(cnt + N);                // [N]
  float* Wf   = invd + N;                         // [L,128,128]
  float* ub   = Wf + (size_t)L * 128 * 128;       // [L,128]
  float* Wm   = ub + (size_t)L * 128;             // [L,128,128]
  float* bfold= Wm + (size_t)L * 128 * 128;       // [L,128]
  unsigned short* hAb = (unsigned short*)(bfold + (size_t)L * 128);  // [N,128] bf16
  unsigned short* Wpk = hAb + (size_t)N * HD;     // [L,16384] bf16 fragments

  hipMemsetAsync(cnt, 0, (size_t)N * sizeof(int), stream);
  hipMemsetAsync(d_out, 0, (size_t)out_size * sizeof(float), stream);

  count_k<<<(E + 255) / 256, 256, 0, stream>>>(ei, cnt, E);
  scan_k<<<1, 1024, 0, stream>>>(cnt, invd, N);
  scatter_k<<<(E + 255) / 256, 256, 0, stream>>>(ei, cnt, spk, E);
  fold_all_k<<<dim3(128, L, 2), 128, 0, stream>>>(m3w2, m2w1, m3b2, m2b1,
                                                  m2w2, m1w1, m2b2, Wf, ub, Wm, bfold);
  pack_k<<<dim3(64, L), 256, 0, stream>>>(Wf, Wpk);

  node_init_k<<<(N + 1) / 2, 256, 0, stream>>>(x, nw1, nb1, buf2, N);
  gemm_node<128, false, false, false, false><<<(N + 127) / 128, 256, 0, stream>>>(
      buf2, nullptr, nullptr, nw2, nullptr, nb2, nullptr, h, N);

  const int nwg = (E + 127) / 128;
  for (int l = 0; l < L; ++l) {
    const float* W2a = m2w1 + (size_t)l * 256 * 128;              // rows 0..127
    const float* W1b = m1w1 + (size_t)l * 256 * 128 + 128 * 128;  // rows 128..255
    // hAb = bf16(h @ W2a)
    gemm_node<128, false, false, false, true><<<(N + 127) / 128, 256, 0, stream>>>(
        h, nullptr, nullptr, W2a, nullptr, nullptr, nullptr, (float*)hAb, N);
    hipMemsetAsync(Pagg, 0, (size_t)N * HD * sizeof(float), stream);
    edge_k<<<nwg, 256, 0, stream>>>(
        spk, pos, hAb,
        m3w1 + (size_t)l * 3 * 128, m3b1 + (size_t)l * 128,
        Wpk + (size_t)l * 16384, ub + (size_t)l * 128,
        Pagg, E, nwg);
    gemm_node<256, true, true, true, false><<<(N + 127) / 128, 256, 0, stream>>>(
        Pagg, h, invd, Wm + (size_t)l * 128 * 128, W1b,
        m1b1 + (size_t)l * 128, bfold + (size_t)l * 128, buf2, N);
    gemm_node<128, true, false, false, false><<<(N + 127) / 128, 256, 0, stream>>>(
        buf2, nullptr, nullptr, m1w2 + (size_t)l * 128 * 128, nullptr,
        m1b2 + (size_t)l * 128, nullptr, h, N);
  }

  readout_k<<<(N + 3) / 4, 256, 0, stream>>>(h, l1w, l1b, l2w, l2b, batch, (float*)d_out, N);
}

// Round 4
// 1068.548 us; speedup vs baseline: 6.9378x; 1.9731x over previous
//
#include <hip/hip_runtime.h>

#define HD 128

typedef __attribute__((ext_vector_type(8))) short bf16x8;
typedef __attribute__((ext_vector_type(4))) float f32x4;

// ---- bf16 helpers ----------------------------------------------------------
__device__ __forceinline__ unsigned rne16(float x) {
  unsigned u = __builtin_bit_cast(unsigned, x);
  return (u + 0x7fffu + ((u >> 16) & 1u)) >> 16;
}
__device__ __forceinline__ unsigned bfpack(float a, float b) {
  return rne16(a) | (rne16(b) << 16);
}
__device__ __forceinline__ float blo(unsigned u) { return __builtin_bit_cast(float, u << 16); }
__device__ __forceinline__ float bhi(unsigned u) { return __builtin_bit_cast(float, u & 0xffff0000u); }

// ---- degree count ----------------------------------------------------------
__global__ void count_k(const int* __restrict__ ei, int* __restrict__ cnt, int E) {
  int e = blockIdx.x * 256 + threadIdx.x;
  if (e < E) atomicAdd(&cnt[ei[E + e]], 1);
}

// ---- single-block exclusive scan -------------------------------------------
__global__ __launch_bounds__(1024) void scan_k(int* __restrict__ cnt,
                                               float* __restrict__ invd, int n) {
  __shared__ int wsum[16];
  const int tid = threadIdx.x;
  const int C = (n + 1023) >> 10;
  const int base = tid * C;
  int local = 0;
  for (int k = 0; k < C; ++k) { int i = base + k; if (i < n) local += cnt[i]; }
  int lane = tid & 63, wid = tid >> 6;
  int v = local;
#pragma unroll
  for (int off = 1; off < 64; off <<= 1) {
    int u = __shfl_up(v, off);
    if (lane >= off) v += u;
  }
  if (lane == 63) wsum[wid] = v;
  __syncthreads();
  if (tid == 0) {
    int s = 0;
    for (int w = 0; w < 16; ++w) { int t = wsum[w]; wsum[w] = s; s += t; }
  }
  __syncthreads();
  int running = v - local + wsum[wid];
  for (int k = 0; k < C; ++k) {
    int i = base + k;
    if (i < n) {
      int c = cnt[i];
      invd[i] = c > 0 ? 1.f / (float)c : 0.f;
      cnt[i] = running;
      running += c;
    }
  }
}

// ---- scatter into dst-sorted order: spk[p] = src | (dst<<16) ---------------
__global__ void scatter_k(const int* __restrict__ ei, int* __restrict__ cur,
                          unsigned int* __restrict__ spk, int E) {
  int e = blockIdx.x * 256 + threadIdx.x;
  if (e >= E) return;
  int s = ei[e], d = ei[E + e];
  int p = atomicAdd(&cur[d], 1);
  spk[p] = (unsigned int)s | ((unsigned int)d << 16);
}

// ---- weight folding --------------------------------------------------------
__global__ void fold_all_k(const float* __restrict__ m3w2, const float* __restrict__ m2w1,
                           const float* __restrict__ m3b2, const float* __restrict__ m2b1,
                           const float* __restrict__ m2w2, const float* __restrict__ m1w1,
                           const float* __restrict__ m2b2,
                           float* __restrict__ Wf, float* __restrict__ ub,
                           float* __restrict__ Wm, float* __restrict__ bf) {
  const int k = blockIdx.x, l = blockIdx.y, mode = blockIdx.z, c = threadIdx.x;
  const float *A, *B, *bA, *badd;
  float *O, *ob;
  if (mode == 0) {
    A = m3w2 + (size_t)l * 128 * 128;
    B = m2w1 + (size_t)l * 256 * 128 + 128 * 128;
    bA = m3b2 + (size_t)l * 128; badd = m2b1 + (size_t)l * 128;
    O = Wf + (size_t)l * 128 * 128; ob = ub + (size_t)l * 128;
  } else {
    A = m2w2 + (size_t)l * 128 * 128;
    B = m1w1 + (size_t)l * 256 * 128;
    bA = m2b2 + (size_t)l * 128; badd = nullptr;
    O = Wm + (size_t)l * 128 * 128; ob = bf + (size_t)l * 128;
  }
  float s = 0.f;
  for (int r = 0; r < 128; ++r) s = fmaf(A[k * 128 + r], B[r * 128 + c], s);
  O[k * 128 + c] = s;
  if (k == 0) {
    float t = badd ? badd[c] : 0.f;
    for (int r = 0; r < 128; ++r) t = fmaf(bA[r], B[r * 128 + c], t);
    ob[c] = t;
  }
}

// ---- pack Wf into bf16 MFMA B-fragment order -------------------------------
__global__ void pack_k(const float* __restrict__ Wf, unsigned short* __restrict__ Wpk) {
  int l = blockIdx.y;
  int flat = blockIdx.x * 256 + threadIdx.x;     // 0..16383
  int e = flat & 7, l6 = (flat >> 3) & 63, ct = (flat >> 9) & 7, kt = flat >> 12;
  int row = kt * 32 + ((l6 >> 4) << 3) + e;
  int col = ct * 16 + (l6 & 15);
  Wpk[(size_t)l * 16384 + flat] =
      (unsigned short)rne16(Wf[(size_t)l * 16384 + row * 128 + col]);
}

// ---- h1 = relu(x * w1 + b1) ------------------------------------------------
__global__ void node_init_k(const float* __restrict__ x, const float* __restrict__ w1,
                            const float* __restrict__ b1, float* __restrict__ h1, int n) {
  int i = blockIdx.x * 2 + (threadIdx.x >> 7);
  int j = threadIdx.x & 127;
  if (i >= n) return;
  float v = fmaf(x[i], w1[j], b1[j]);
  h1[(size_t)i * HD + j] = v > 0.f ? v : 0.f;
}

// ---- node GEMM (fp32 VALU) -------------------------------------------------
template<int K, bool RELU, bool SCALE0, bool BIAS2, bool OUTBF16>
__global__ __launch_bounds__(256) void gemm_node(
    const float* __restrict__ in0, const float* __restrict__ in1,
    const float* __restrict__ sc,
    const float* __restrict__ W0, const float* __restrict__ W1,
    const float* __restrict__ bias, const float* __restrict__ bias2,
    float* __restrict__ out, int M)
{
  __shared__ float A[16][132];
  __shared__ float B[16][132];
  const int tid = threadIdx.x;
  const int ty = tid >> 4, tx = tid & 15;
  const int m0 = blockIdx.x * 128;

  float acc[8][8];
#pragma unroll
  for (int i = 0; i < 8; ++i)
#pragma unroll
    for (int j = 0; j < 8; ++j) acc[i][j] = 0.f;

  for (int kc = 0; kc < K; kc += 16) {
    __syncthreads();
    {
      int m = tid >> 1, kh = (tid & 1) * 8;
      int gm = m0 + m, kk = kc + kh;
      float4 v0 = {0,0,0,0}, v1 = {0,0,0,0};
      if (gm < M) {
        const float* base = (K == 256 && kk >= 128) ? (in1 + (size_t)gm * HD + (kk - 128))
                                                    : (in0 + (size_t)gm * HD + kk);
        v0 = *(const float4*)base;
        v1 = *(const float4*)(base + 4);
        if (SCALE0 && kk < 128) {
          float s = sc[gm];
          v0.x *= s; v0.y *= s; v0.z *= s; v0.w *= s;
          v1.x *= s; v1.y *= s; v1.z *= s; v1.w *= s;
        }
      }
      A[kh+0][m] = v0.x; A[kh+1][m] = v0.y; A[kh+2][m] = v0.z; A[kh+3][m] = v0.w;
      A[kh+4][m] = v1.x; A[kh+5][m] = v1.y; A[kh+6][m] = v1.z; A[kh+7][m] = v1.w;
    }
    {
      int k = tid >> 4, c = (tid & 15) * 8;
      const float* Wsrc = (K == 256 && kc >= 128) ? (W1 + (size_t)(kc - 128 + k) * HD)
                                                  : (W0 + (size_t)(kc + k) * HD);
      *(float4*)&B[k][c]   = *(const float4*)&Wsrc[c];
      *(float4*)&B[k][c+4] = *(const float4*)&Wsrc[c + 4];
    }
    __syncthreads();
#pragma unroll
    for (int kk = 0; kk < 16; ++kk) {
      float4 a0 = *(const float4*)&A[kk][ty*8];
      float4 a1 = *(const float4*)&A[kk][ty*8+4];
      float4 b0 = *(const float4*)&B[kk][tx*8];
      float4 b1 = *(const float4*)&B[kk][tx*8+4];
      float av[8] = {a0.x,a0.y,a0.z,a0.w,a1.x,a1.y,a1.z,a1.w};
      float bv[8] = {b0.x,b0.y,b0.z,b0.w,b1.x,b1.y,b1.z,b1.w};
#pragma unroll
      for (int i = 0; i < 8; ++i)
#pragma unroll
        for (int j = 0; j < 8; ++j) acc[i][j] = fmaf(av[i], bv[j], acc[i][j]);
    }
  }

  float bv[8];
  if (bias) {
    float4 b0 = *(const float4*)&bias[tx*8];
    float4 b1 = *(const float4*)&bias[tx*8+4];
    bv[0]=b0.x; bv[1]=b0.y; bv[2]=b0.z; bv[3]=b0.w;
    bv[4]=b1.x; bv[5]=b1.y; bv[6]=b1.z; bv[7]=b1.w;
  } else {
#pragma unroll
    for (int j = 0; j < 8; ++j) bv[j] = 0.f;
  }
  float b2v[8] = {0,0,0,0,0,0,0,0};
  if (BIAS2) {
    float4 c0 = *(const float4*)&bias2[tx*8];
    float4 c1 = *(const float4*)&bias2[tx*8+4];
    b2v[0]=c0.x; b2v[1]=c0.y; b2v[2]=c0.z; b2v[3]=c0.w;
    b2v[4]=c1.x; b2v[5]=c1.y; b2v[6]=c1.z; b2v[7]=c1.w;
  }
#pragma unroll
  for (int i = 0; i < 8; ++i) {
    int gm = m0 + ty*8 + i;
    if (gm < M) {
      float m2 = 0.f;
      if (BIAS2) m2 = (sc[gm] > 0.f) ? 1.f : 0.f;
      float o[8];
#pragma unroll
      for (int j = 0; j < 8; ++j) {
        float v = acc[i][j] + bv[j] + (BIAS2 ? m2 * b2v[j] : 0.f);
        o[j] = (RELU && v < 0.f) ? 0.f : v;
      }
      if (OUTBF16) {
        unsigned short* ob = (unsigned short*)out;
        uint4 pk;
        pk.x = bfpack(o[0], o[1]); pk.y = bfpack(o[2], o[3]);
        pk.z = bfpack(o[4], o[5]); pk.w = bfpack(o[6], o[7]);
        *(uint4*)&ob[(size_t)gm * HD + tx*8] = pk;
      } else {
        float4 s0 = {o[0],o[1],o[2],o[3]}, s1 = {o[4],o[5],o[6],o[7]};
        *(float4*)&out[(size_t)gm * HD + tx*8]     = s0;
        *(float4*)&out[(size_t)gm * HD + tx*8 + 4] = s1;
      }
    }
  }
}

// ---- fused edge kernel: MFMA bf16 GEMM + segment reduce, mostly-plain stores
__global__ __launch_bounds__(256, 4) void edge_k(
    const unsigned int* __restrict__ spk, const float* __restrict__ pos,
    const unsigned short* __restrict__ hAb,
    const float* __restrict__ w31, const float* __restrict__ b31,
    const unsigned short* __restrict__ Wpk, const float* __restrict__ ub,
    float* __restrict__ Pagg, int E, int nwg)
{
  __shared__ __align__(16) unsigned short Tw[128 * 128];  // t (swizzled) -> u -> P
  __shared__ int SS[128];
  __shared__ int SD[128];
  __shared__ int segstart[132];
  __shared__ int segdst[132];
  __shared__ int sScal[4];   // 0:dprev 1:dnext 2:cnt0 3:nseg
  const int tid = threadIdx.x;
  const int lane = tid & 63, w4 = tid >> 6;

  // XCD-bijective block swizzle
  int b = blockIdx.x;
  int q = nwg >> 3, r = nwg & 7;
  int xcd = b & 7, sub = b >> 3;
  int wg = (xcd < r ? xcd * (q + 1) : r * (q + 1) + (xcd - r) * q) + sub;
  const int e0 = wg * 128;

  // ---- stage 1: t = relu(dist @ w31 + b31) -> bf16 LDS (A-frag layout) -----
  {
    int el = tid & 127;
    int p = e0 + el;
    int s = 0, d = -1;
    float d0 = 0.f, d1 = 0.f, d2 = 0.f;
    if (p < E) {
      unsigned int pk = spk[p];
      s = (int)(pk & 0xffffu);
      d = (int)(pk >> 16);
      d0 = pos[(size_t)s*3+0] - pos[(size_t)d*3+0];
      d1 = pos[(size_t)s*3+1] - pos[(size_t)d*3+1];
      d2 = pos[(size_t)s*3+2] - pos[(size_t)d*3+2];
    }
    if (tid < 128) { SS[tid] = s; SD[tid] = d; }
    if (tid == 0) sScal[0] = (e0 > 0) ? (int)(spk[e0-1] >> 16) : -2;
    if (tid == 1) sScal[1] = (e0 + 128 < E) ? (int)(spk[e0+128] >> 16) : -2;
    int k0 = (tid >> 7) * 64;
    int swz = el & 7;
#pragma unroll
    for (int g = 0; g < 8; ++g) {
      int kb = (k0 >> 3) + g;
      float v[8];
#pragma unroll
      for (int j = 0; j < 8; ++j) {
        int k = k0 + g*8 + j;
        float t = fmaf(d0, w31[k], fmaf(d1, w31[128+k], fmaf(d2, w31[256+k], b31[k])));
        v[j] = t > 0.f ? t : 0.f;
      }
      uint4 w;
      w.x = bfpack(v[0], v[1]); w.y = bfpack(v[2], v[3]);
      w.z = bfpack(v[4], v[5]); w.w = bfpack(v[6], v[7]);
      *(uint4*)&Tw[el * 128 + ((kb ^ swz) << 3)] = w;
    }
  }
  __syncthreads();

  // ---- segment scan over SD (2-wave ballot), overlapped with gather issue --
  bool head = false;
  if (tid < 128) {
    int d = SD[tid];
    head = (tid == 0) ? true : (d != SD[tid - 1]);
  }
  unsigned long long bal = __ballot(head);
  int rank = __popcll(bal & ((1ull << lane) - 1));
  if (tid == 0) sScal[2] = 0;  // placeholder, set below
  if (tid == 63) sScal[2] = rank + (head ? 1 : 0);  // count of wave0 heads

  // prefetch hA rows for this thread's 8 edges (hidden under the GEMM)
  const int ty = tid >> 4, tx = tid & 15;
  uint4 hv[8];
#pragma unroll
  for (int i = 0; i < 8; ++i) {
    int s = SS[ty*8 + i];
    hv[i] = *(const uint4*)&hAb[(size_t)s * HD + tx*8];
  }
  __syncthreads();   // sScal[2] ready
  if (tid < 128) {
    int rr = rank + ((tid >= 64) ? sScal[2] : 0);
    if (head) { segstart[rr] = tid; segdst[rr] = SD[tid]; }
  }
  if (tid == 64) sScal[3] = sScal[2] + __popcll(bal);
  if (tid == 65 && ((tid & 127) >= 64)) {}  // no-op

  // ---- stage 2: u = t @ Wf via MFMA ----------------------------------------
  const int lrow = lane & 15, lk = lane >> 4;
  f32x4 acc[2][8];
#pragma unroll
  for (int rt = 0; rt < 2; ++rt)
#pragma unroll
    for (int ct = 0; ct < 8; ++ct) acc[rt][ct] = (f32x4){0.f, 0.f, 0.f, 0.f};

#pragma unroll
  for (int kt = 0; kt < 4; ++kt) {
    bf16x8 a[2];
#pragma unroll
    for (int rt = 0; rt < 2; ++rt) {
      int e = w4*32 + rt*16 + lrow;
      int kb = kt*4 + lk;
      a[rt] = *(const bf16x8*)&Tw[e * 128 + ((kb ^ (e & 7)) << 3)];
    }
#pragma unroll
    for (int cg = 0; cg < 2; ++cg) {
      bf16x8 bq[4];
#pragma unroll
      for (int c4 = 0; c4 < 4; ++c4)
        bq[c4] = *(const bf16x8*)&Wpk[(size_t)(((kt*8 + cg*4 + c4) * 64) + lane) * 8];
#pragma unroll
      for (int rt = 0; rt < 2; ++rt)
#pragma unroll
        for (int c4 = 0; c4 < 4; ++c4)
          acc[rt][cg*4 + c4] = __builtin_amdgcn_mfma_f32_16x16x32_bf16(
              a[rt], bq[c4], acc[rt][cg*4 + c4], 0, 0, 0);
    }
  }
  __syncthreads();   // all t reads done; also covers segstart/segdst/nseg writes

  // ---- write u (bf16) into Tw as [e][c] -------------------------------------
#pragma unroll
  for (int rt = 0; rt < 2; ++rt) {
    int ebase = w4*32 + rt*16 + lk*4;
#pragma unroll
    for (int ct = 0; ct < 8; ++ct) {
      int c = ct*16 + lrow;
      Tw[(ebase+0)*128 + c] = (unsigned short)rne16(acc[rt][ct][0]);
      Tw[(ebase+1)*128 + c] = (unsigned short)rne16(acc[rt][ct][1]);
      Tw[(ebase+2)*128 + c] = (unsigned short)rne16(acc[rt][ct][2]);
      Tw[(ebase+3)*128 + c] = (unsigned short)rne16(acc[rt][ct][3]);
    }
  }
  __syncthreads();

  // ---- P = relu(u + hA[src] + ub) written back in place (bf16) -------------
  {
    float4 u0 = *(const float4*)&ub[tx*8];
    float4 u1 = *(const float4*)&ub[tx*8+4];
    float ubv[8] = {u0.x,u0.y,u0.z,u0.w,u1.x,u1.y,u1.z,u1.w};
#pragma unroll
    for (int i = 0; i < 8; ++i) {
      int row = ty*8 + i;
      uint4 uv = *(const uint4*)&Tw[row * 128 + tx*8];
      float uvv[8] = {blo(uv.x),bhi(uv.x),blo(uv.y),bhi(uv.y),
                      blo(uv.z),bhi(uv.z),blo(uv.w),bhi(uv.w)};
      float hvv[8] = {blo(hv[i].x),bhi(hv[i].x),blo(hv[i].y),bhi(hv[i].y),
                      blo(hv[i].z),bhi(hv[i].z),blo(hv[i].w),bhi(hv[i].w)};
      float p[8];
#pragma unroll
      for (int j = 0; j < 8; ++j) {
        float v = uvv[j] + hvv[j] + ubv[j];
        p[j] = v > 0.f ? v : 0.f;
      }
      uint4 w;
      w.x = bfpack(p[0], p[1]); w.y = bfpack(p[2], p[3]);
      w.z = bfpack(p[4], p[5]); w.w = bfpack(p[6], p[7]);
      *(uint4*)&Tw[row * 128 + tx*8] = w;
    }
  }
  __syncthreads();

  // ---- segment reduce: one wave per segment; plain store unless boundary ---
  {
    const int nseg = sScal[3];
    const int dprev = sScal[0], dnext = sScal[1];
    for (int s = w4; s < nseg; s += 4) {
      int dst = segdst[s];
      if (dst < 0) continue;
      int r0 = segstart[s];
      int r1 = (s + 1 < nseg) ? segstart[s + 1] : 128;
      float sx = 0.f, sy = 0.f;
      for (int rr = r0; rr < r1; ++rr) {
        unsigned v = *(const unsigned*)&Tw[rr * 128 + lane * 2];
        sx += blo(v); sy += bhi(v);
      }
      float* pp = &Pagg[(size_t)dst * HD + lane * 2];
      if (dst == dprev || dst == dnext) {
        atomicAdd(pp, sx);
        atomicAdd(pp + 1, sy);
      } else {
        float2 st = {sx, sy};
        *(float2*)pp = st;
      }
    }
  }
}

// ---- readout: l1w cached in LDS, wave per node ------------------------------
__global__ __launch_bounds__(256) void readout_k(
    const float* __restrict__ h, const float* __restrict__ l1w, const float* __restrict__ l1b,
    const float* __restrict__ l2w, const float* __restrict__ l2b,
    const int* __restrict__ batch, float* __restrict__ out, int n)
{
  __shared__ float Lw[128 * 64];
  __shared__ float Lb[64], L2c[64];
  const int tid = threadIdx.x;
  for (int i = tid; i < 128 * 64; i += 256) Lw[i] = l1w[i];
  if (tid < 64) { Lb[tid] = l1b[tid]; L2c[tid] = l2w[tid]; }
  __syncthreads();
  const int lane = tid & 63, wid = tid >> 6;
  const float l2b0 = l2b[0];
  for (int node = blockIdx.x * 4 + wid; node < n; node += gridDim.x * 4) {
    const float* hr = h + (size_t)node * HD;
    float z = Lb[lane];
#pragma unroll 8
    for (int k = 0; k < 128; ++k) z = fmaf(hr[k], Lw[k * 64 + lane], z);
    float y = (z > 0.f ? z : 0.f) * L2c[lane];
#pragma unroll
    for (int off = 32; off > 0; off >>= 1) y += __shfl_down(y, off);
    if (lane == 0) atomicAdd(&out[batch[node]], y + l2b0);
  }
}

extern "C" void kernel_launch(void* const* d_in, const int* in_sizes, int n_in,
                              void* d_out, int out_size, void* d_ws, size_t ws_size,
                              hipStream_t stream) {
  const float* x     = (const float*)d_in[0];
  const float* pos   = (const float*)d_in[1];
  const int*   ei    = (const int*)d_in[2];
  const int*   batch = (const int*)d_in[3];
  const float* nw1   = (const float*)d_in[4];
  const float* nb1   = (const float*)d_in[5];
  const float* nw2   = (const float*)d_in[6];
  const float* nb2   = (const float*)d_in[7];
  const float* m1w1  = (const float*)d_in[8];
  const float* m1b1  = (const float*)d_in[9];
  const float* m1w2  = (const float*)d_in[10];
  const float* m1b2  = (const float*)d_in[11];
  const float* m2w1  = (const float*)d_in[12];
  const float* m2b1  = (const float*)d_in[13];
  const float* m2w2  = (const float*)d_in[14];
  const float* m2b2  = (const float*)d_in[15];
  const float* m3w1  = (const float*)d_in[16];
  const float* m3b1  = (const float*)d_in[17];
  const float* m3w2  = (const float*)d_in[18];
  const float* m3b2  = (const float*)d_in[19];
  const float* l1w   = (const float*)d_in[20];
  const float* l1b   = (const float*)d_in[21];
  const float* l2w   = (const float*)d_in[22];
  const float* l2b   = (const float*)d_in[23];

  const int N = in_sizes[0];
  const int E = in_sizes[2] / 2;
  const int L = in_sizes[8] / (256 * 128);

  float* h    = (float*)d_ws;                     // [N,128]
  float* buf2 = h    + (size_t)N * HD;            // tmp [N,128]
  float* Pagg = buf2 + (size_t)N * HD;            // [N,128]
  unsigned int* spk = (unsigned int*)(Pagg + (size_t)N * HD);  // [E]
  int*   cnt  = (int*)(spk + E);                  // [N]
  float* invd = (float*)(cnt + N);                // [N]
  float* Wf   = invd + N;                         // [L,128,128]
  float* ub   = Wf + (size_t)L * 128 * 128;       // [L,128]
  float* Wm   = ub + (size_t)L * 128;             // [L,128,128]
  float* bfold= Wm + (size_t)L * 128 * 128;       // [L,128]
  unsigned short* hAb = (unsigned short*)(bfold + (size_t)L * 128);  // [N,128] bf16
  unsigned short* Wpk = hAb + (size_t)N * HD;     // [L,16384] bf16 fragments

  hipMemsetAsync(cnt, 0, (size_t)N * sizeof(int), stream);
  hipMemsetAsync(d_out, 0, (size_t)out_size * sizeof(float), stream);

  count_k<<<(E + 255) / 256, 256, 0, stream>>>(ei, cnt, E);
  scan_k<<<1, 1024, 0, stream>>>(cnt, invd, N);
  scatter_k<<<(E + 255) / 256, 256, 0, stream>>>(ei, cnt, spk, E);
  fold_all_k<<<dim3(128, L, 2), 128, 0, stream>>>(m3w2, m2w1, m3b2, m2b1,
                                                  m2w2, m1w1, m2b2, Wf, ub, Wm, bfold);
  pack_k<<<dim3(64, L), 256, 0, stream>>>(Wf, Wpk);

  node_init_k<<<(N + 1) / 2, 256, 0, stream>>>(x, nw1, nb1, buf2, N);
  gemm_node<128, false, false, false, false><<<(N + 127) / 128, 256, 0, stream>>>(
      buf2, nullptr, nullptr, nw2, nullptr, nb2, nullptr, h, N);

  const int nwg = (E + 127) / 128;
  for (int l = 0; l < L; ++l) {
    const float* W2a = m2w1 + (size_t)l * 256 * 128;              // rows 0..127
    const float* W1b = m1w1 + (size_t)l * 256 * 128 + 128 * 128;  // rows 128..255
    // hAb = bf16(h @ W2a)
    gemm_node<128, false, false, false, true><<<(N + 127) / 128, 256, 0, stream>>>(
        h, nullptr, nullptr, W2a, nullptr, nullptr, nullptr, (float*)hAb, N);
    hipMemsetAsync(Pagg, 0, (size_t)N * HD * sizeof(float), stream);
    edge_k<<<nwg, 256, 0, stream>>>(
        spk, pos, hAb,
        m3w1 + (size_t)l * 3 * 128, m3b1 + (size_t)l * 128,
        Wpk + (size_t)l * 16384, ub + (size_t)l * 128,
        Pagg, E, nwg);
    gemm_node<256, true, true, true, false><<<(N + 127) / 128, 256, 0, stream>>>(
        Pagg, h, invd, Wm + (size_t)l * 128 * 128, W1b,
        m1b1 + (size_t)l * 128, bfold + (size_t)l * 128, buf2, N);
    gemm_node<128, true, false, false, false><<<(N + 127) / 128, 256, 0, stream>>>(
        buf2, nullptr, nullptr, m1w2 + (size_t)l * 128 * 128, nullptr,
        m1b2 + (size_t)l * 128, nullptr, h, N);
  }

  readout_k<<<2048, 256, 0, stream>>>(h, l1w, l1b, l2w, l2b, batch, (float*)d_out, N);
}

// Round 5
// 782.272 us; speedup vs baseline: 9.4767x; 1.3660x over previous
//
#include <hip/hip_runtime.h>

#define HD 128

typedef __attribute__((ext_vector_type(8))) short bf16x8;
typedef __attribute__((ext_vector_type(4))) float f32x4;

// ---- bf16 helpers ----------------------------------------------------------
__device__ __forceinline__ unsigned rne16(float x) {
  unsigned u = __builtin_bit_cast(unsigned, x);
  return (u + 0x7fffu + ((u >> 16) & 1u)) >> 16;
}
__device__ __forceinline__ unsigned bfpack(float a, float b) {
  return rne16(a) | (rne16(b) << 16);
}
__device__ __forceinline__ float blo(unsigned u) { return __builtin_bit_cast(float, u << 16); }
__device__ __forceinline__ float bhi(unsigned u) { return __builtin_bit_cast(float, u & 0xffff0000u); }
__device__ __forceinline__ float bval(unsigned h16) { return __builtin_bit_cast(float, h16 << 16); }

// split v into hi/lo bf16 (stored as ushort)
__device__ __forceinline__ void bsplit(float v, unsigned short& hi, unsigned short& lo) {
  unsigned h = rne16(v);
  hi = (unsigned short)h;
  lo = (unsigned short)rne16(v - bval(h));
}

// ---- degree count ----------------------------------------------------------
__global__ void count_k(const int* __restrict__ ei, int* __restrict__ cnt, int E) {
  int e = blockIdx.x * 256 + threadIdx.x;
  if (e < E) atomicAdd(&cnt[ei[E + e]], 1);
}

// ---- single-block exclusive scan -------------------------------------------
__global__ __launch_bounds__(1024) void scan_k(int* __restrict__ cnt,
                                               float* __restrict__ invd, int n) {
  __shared__ int wsum[16];
  const int tid = threadIdx.x;
  const int C = (n + 1023) >> 10;
  const int base = tid * C;
  int local = 0;
  for (int k = 0; k < C; ++k) { int i = base + k; if (i < n) local += cnt[i]; }
  int lane = tid & 63, wid = tid >> 6;
  int v = local;
#pragma unroll
  for (int off = 1; off < 64; off <<= 1) {
    int u = __shfl_up(v, off);
    if (lane >= off) v += u;
  }
  if (lane == 63) wsum[wid] = v;
  __syncthreads();
  if (tid == 0) {
    int s = 0;
    for (int w = 0; w < 16; ++w) { int t = wsum[w]; wsum[w] = s; s += t; }
  }
  __syncthreads();
  int running = v - local + wsum[wid];
  for (int k = 0; k < C; ++k) {
    int i = base + k;
    if (i < n) {
      int c = cnt[i];
      invd[i] = c > 0 ? 1.f / (float)c : 0.f;
      cnt[i] = running;
      running += c;
    }
  }
}

// ---- scatter into dst-sorted order: spk[p] = src | (dst<<16) ---------------
__global__ void scatter_k(const int* __restrict__ ei, int* __restrict__ cur,
                          unsigned int* __restrict__ spk, int E) {
  int e = blockIdx.x * 256 + threadIdx.x;
  if (e >= E) return;
  int s = ei[e], d = ei[E + e];
  int p = atomicAdd(&cur[d], 1);
  spk[p] = (unsigned int)s | ((unsigned int)d << 16);
}

// ---- weight folding --------------------------------------------------------
__global__ void fold_all_k(const float* __restrict__ m3w2, const float* __restrict__ m2w1,
                           const float* __restrict__ m3b2, const float* __restrict__ m2b1,
                           const float* __restrict__ m2w2, const float* __restrict__ m1w1,
                           const float* __restrict__ m2b2,
                           float* __restrict__ Wf, float* __restrict__ ub,
                           float* __restrict__ Wm, float* __restrict__ bf) {
  const int k = blockIdx.x, l = blockIdx.y, mode = blockIdx.z, c = threadIdx.x;
  const float *A, *B, *bA, *badd;
  float *O, *ob;
  if (mode == 0) {
    A = m3w2 + (size_t)l * 128 * 128;
    B = m2w1 + (size_t)l * 256 * 128 + 128 * 128;
    bA = m3b2 + (size_t)l * 128; badd = m2b1 + (size_t)l * 128;
    O = Wf + (size_t)l * 128 * 128; ob = ub + (size_t)l * 128;
  } else {
    A = m2w2 + (size_t)l * 128 * 128;
    B = m1w1 + (size_t)l * 256 * 128;
    bA = m2b2 + (size_t)l * 128; badd = nullptr;
    O = Wm + (size_t)l * 128 * 128; ob = bf + (size_t)l * 128;
  }
  float s = 0.f;
  for (int r = 0; r < 128; ++r) s = fmaf(A[k * 128 + r], B[r * 128 + c], s);
  O[k * 128 + c] = s;
  if (k == 0) {
    float t = badd ? badd[c] : 0.f;
    for (int r = 0; r < 128; ++r) t = fmaf(bA[r], B[r * 128 + c], t);
    ob[c] = t;
  }
}

// ---- pack Wf into bf16 MFMA B-fragment order (for edge_k) ------------------
__global__ void pack_k(const float* __restrict__ Wf, unsigned short* __restrict__ Wpk) {
  int l = blockIdx.y;
  int flat = blockIdx.x * 256 + threadIdx.x;     // 0..16383
  int e = flat & 7, l6 = (flat >> 3) & 63, ct = (flat >> 9) & 7, kt = flat >> 12;
  int row = kt * 32 + ((l6 >> 4) << 3) + e;
  int col = ct * 16 + (l6 & 15);
  Wpk[(size_t)l * 16384 + flat] =
      (unsigned short)rne16(Wf[(size_t)l * 16384 + row * 128 + col]);
}

// ---- node GEMM via MFMA with hi/lo bf16 split (~fp32 precision) ------------
// out[M][128] = act( [sc.*in0 | in1] @ [W0;W1] + bias + [sc>0]*bias2 )
// AINIT: A row r = relu(in0[r]*aw[k] + ab[k])   (fused node_init)
template<int KT, bool RELU, bool SCALE0, bool BIAS2, bool OUTBF16, bool AINIT>
__global__ __launch_bounds__(256, 2) void gemm_mfma(
    const float* __restrict__ in0, const float* __restrict__ in1,
    const float* __restrict__ sc,
    const float* __restrict__ W0, const float* __restrict__ W1,
    const float* __restrict__ bias, const float* __restrict__ bias2,
    const float* __restrict__ aw, const float* __restrict__ ab,
    float* __restrict__ out, int M)
{
  __shared__ __align__(16) unsigned short Wh[16384];   // B-frag hi (128 k-rows)
  __shared__ __align__(16) unsigned short Wl[16384];   // B-frag lo
  const int tid = threadIdx.x;
  const int lane = tid & 63, w4 = tid >> 6;
  const int lrow = lane & 15, lk = lane >> 4;
  const int m0 = blockIdx.x * 128;

  // per-wave rows
  int rown[2];
  bool valid[2];
  float scl[2], xv[2];
#pragma unroll
  for (int rt = 0; rt < 2; ++rt) {
    rown[rt] = m0 + w4 * 32 + rt * 16 + lrow;
    valid[rt] = rown[rt] < M;
    scl[rt] = (SCALE0 && valid[rt]) ? sc[rown[rt]] : 1.f;
    xv[rt] = (AINIT && valid[rt]) ? in0[rown[rt]] : 0.f;
  }

  f32x4 acc[2][8];
#pragma unroll
  for (int rt = 0; rt < 2; ++rt)
#pragma unroll
    for (int ct = 0; ct < 8; ++ct) acc[rt][ct] = (f32x4){0.f, 0.f, 0.f, 0.f};

  const int KH = KT / 4;   // 1 or 2 halves of 128 k-rows
  for (int kh = 0; kh < KH; ++kh) {
    __syncthreads();
    // stage W half [kh*128, kh*128+128) into hi/lo B-frag layout
    for (int it = 0; it < 8; ++it) {
      int g = tid + it * 256;              // group in [0,2048)
      int kt = g >> 9, ct = (g >> 6) & 7, ln = g & 63;
      int rloc = kt * 32 + ((ln >> 4) << 3);
      int col = ct * 16 + (ln & 15);
      int kglob = kh * 128 + rloc;
      const float* Wsrc = (KT == 8 && kglob >= 128) ? (W1 + (size_t)(kglob - 128) * HD)
                                                    : (W0 + (size_t)kglob * HD);
      unsigned short h8[8], l8[8];
#pragma unroll
      for (int e = 0; e < 8; ++e) bsplit(Wsrc[(size_t)e * HD + col], h8[e], l8[e]);
      uint4 ph = {(unsigned)h8[0] | ((unsigned)h8[1] << 16),
                  (unsigned)h8[2] | ((unsigned)h8[3] << 16),
                  (unsigned)h8[4] | ((unsigned)h8[5] << 16),
                  (unsigned)h8[6] | ((unsigned)h8[7] << 16)};
      uint4 pl = {(unsigned)l8[0] | ((unsigned)l8[1] << 16),
                  (unsigned)l8[2] | ((unsigned)l8[3] << 16),
                  (unsigned)l8[4] | ((unsigned)l8[5] << 16),
                  (unsigned)l8[6] | ((unsigned)l8[7] << 16)};
      *(uint4*)&Wh[g * 8] = ph;
      *(uint4*)&Wl[g * 8] = pl;
    }
    __syncthreads();

    for (int ktl = 0; ktl < 4; ++ktl) {
      const int ktg = kh * 4 + ktl;
      const int k0 = ktg * 32 + lk * 8;
      // A fragments (hi/lo) straight from global
      bf16x8 ah[2], al[2];
      float awv[8];
      if (AINIT) {
        float4 a0 = *(const float4*)&aw[k0];
        float4 a1 = *(const float4*)&aw[k0 + 4];
        float4 b0 = *(const float4*)&ab[k0];
        float4 b1 = *(const float4*)&ab[k0 + 4];
        awv[0]=a0.x; awv[1]=a0.y; awv[2]=a0.z; awv[3]=a0.w;
        awv[4]=a1.x; awv[5]=a1.y; awv[6]=a1.z; awv[7]=a1.w;
        float abv[8] = {b0.x,b0.y,b0.z,b0.w,b1.x,b1.y,b1.z,b1.w};
#pragma unroll
        for (int rt = 0; rt < 2; ++rt) {
          unsigned short h8[8], l8[8];
#pragma unroll
          for (int e = 0; e < 8; ++e) {
            float v = fmaf(xv[rt], awv[e], abv[e]);
            v = v > 0.f ? v : 0.f;
            bsplit(v, h8[e], l8[e]);
          }
          ah[rt] = *(bf16x8*)h8; al[rt] = *(bf16x8*)l8;
        }
      } else {
#pragma unroll
        for (int rt = 0; rt < 2; ++rt) {
          float v[8] = {0,0,0,0,0,0,0,0};
          if (valid[rt]) {
            const float* base = (KT == 8 && k0 >= 128)
                                ? (in1 + (size_t)rown[rt] * HD + (k0 - 128))
                                : (in0 + (size_t)rown[rt] * HD + k0);
            float4 v0 = *(const float4*)base;
            float4 v1 = *(const float4*)(base + 4);
            v[0]=v0.x; v[1]=v0.y; v[2]=v0.z; v[3]=v0.w;
            v[4]=v1.x; v[5]=v1.y; v[6]=v1.z; v[7]=v1.w;
            if (SCALE0 && k0 < 128) {
#pragma unroll
              for (int e = 0; e < 8; ++e) v[e] *= scl[rt];
            }
          }
          unsigned short h8[8], l8[8];
#pragma unroll
          for (int e = 0; e < 8; ++e) bsplit(v[e], h8[e], l8[e]);
          ah[rt] = *(bf16x8*)h8; al[rt] = *(bf16x8*)l8;
        }
      }
#pragma unroll
      for (int ct = 0; ct < 8; ++ct) {
        bf16x8 bh = *(const bf16x8*)&Wh[(((ktl * 8 + ct) * 64) + lane) * 8];
        bf16x8 bl = *(const bf16x8*)&Wl[(((ktl * 8 + ct) * 64) + lane) * 8];
#pragma unroll
        for (int rt = 0; rt < 2; ++rt) {
          acc[rt][ct] = __builtin_amdgcn_mfma_f32_16x16x32_bf16(ah[rt], bh, acc[rt][ct], 0, 0, 0);
          acc[rt][ct] = __builtin_amdgcn_mfma_f32_16x16x32_bf16(al[rt], bh, acc[rt][ct], 0, 0, 0);
          acc[rt][ct] = __builtin_amdgcn_mfma_f32_16x16x32_bf16(ah[rt], bl, acc[rt][ct], 0, 0, 0);
        }
      }
    }
  }

  // epilogue: C layout row=(lane>>4)*4+reg, col=lane&15 within 16x16 tile
#pragma unroll
  for (int rt = 0; rt < 2; ++rt) {
    int rbase = m0 + w4 * 32 + rt * 16 + lk * 4;
    float m2[4];
#pragma unroll
    for (int reg = 0; reg < 4; ++reg) {
      int row = rbase + reg;
      m2[reg] = (BIAS2 && row < M && sc[row] > 0.f) ? 1.f : 0.f;
    }
#pragma unroll
    for (int ct = 0; ct < 8; ++ct) {
      int col = ct * 16 + lrow;
      float bv = bias ? bias[col] : 0.f;
      float b2v = BIAS2 ? bias2[col] : 0.f;
#pragma unroll
      for (int reg = 0; reg < 4; ++reg) {
        int row = rbase + reg;
        if (row < M) {
          float v = acc[rt][ct][reg] + bv + m2[reg] * b2v;
          if (RELU && v < 0.f) v = 0.f;
          if (OUTBF16) ((unsigned short*)out)[(size_t)row * HD + col] = (unsigned short)rne16(v);
          else out[(size_t)row * HD + col] = v;
        }
      }
    }
  }
}

// ---- fused edge kernel (unchanged from round 4) ----------------------------
__global__ __launch_bounds__(256, 4) void edge_k(
    const unsigned int* __restrict__ spk, const float* __restrict__ pos,
    const unsigned short* __restrict__ hAb,
    const float* __restrict__ w31, const float* __restrict__ b31,
    const unsigned short* __restrict__ Wpk, const float* __restrict__ ub,
    float* __restrict__ Pagg, int E, int nwg)
{
  __shared__ __align__(16) unsigned short Tw[128 * 128];
  __shared__ int SS[128];
  __shared__ int SD[128];
  __shared__ int segstart[132];
  __shared__ int segdst[132];
  __shared__ int sScal[4];
  const int tid = threadIdx.x;
  const int lane = tid & 63, w4 = tid >> 6;

  int b = blockIdx.x;
  int q = nwg >> 3, r = nwg & 7;
  int xcd = b & 7, sub = b >> 3;
  int wg = (xcd < r ? xcd * (q + 1) : r * (q + 1) + (xcd - r) * q) + sub;
  const int e0 = wg * 128;

  {
    int el = tid & 127;
    int p = e0 + el;
    int s = 0, d = -1;
    float d0 = 0.f, d1 = 0.f, d2 = 0.f;
    if (p < E) {
      unsigned int pk = spk[p];
      s = (int)(pk & 0xffffu);
      d = (int)(pk >> 16);
      d0 = pos[(size_t)s*3+0] - pos[(size_t)d*3+0];
      d1 = pos[(size_t)s*3+1] - pos[(size_t)d*3+1];
      d2 = pos[(size_t)s*3+2] - pos[(size_t)d*3+2];
    }
    if (tid < 128) { SS[tid] = s; SD[tid] = d; }
    if (tid == 0) sScal[0] = (e0 > 0) ? (int)(spk[e0-1] >> 16) : -2;
    if (tid == 1) sScal[1] = (e0 + 128 < E) ? (int)(spk[e0+128] >> 16) : -2;
    int k0 = (tid >> 7) * 64;
    int swz = el & 7;
#pragma unroll
    for (int g = 0; g < 8; ++g) {
      int kb = (k0 >> 3) + g;
      float v[8];
#pragma unroll
      for (int j = 0; j < 8; ++j) {
        int k = k0 + g*8 + j;
        float t = fmaf(d0, w31[k], fmaf(d1, w31[128+k], fmaf(d2, w31[256+k], b31[k])));
        v[j] = t > 0.f ? t : 0.f;
      }
      uint4 w;
      w.x = bfpack(v[0], v[1]); w.y = bfpack(v[2], v[3]);
      w.z = bfpack(v[4], v[5]); w.w = bfpack(v[6], v[7]);
      *(uint4*)&Tw[el * 128 + ((kb ^ swz) << 3)] = w;
    }
  }
  __syncthreads();

  bool head = false;
  if (tid < 128) {
    int d = SD[tid];
    head = (tid == 0) ? true : (d != SD[tid - 1]);
  }
  unsigned long long bal = __ballot(head);
  int rank = __popcll(bal & ((1ull << lane) - 1));
  if (tid == 0) sScal[2] = 0;
  if (tid == 63) sScal[2] = rank + (head ? 1 : 0);

  const int ty = tid >> 4, tx = tid & 15;
  uint4 hv[8];
#pragma unroll
  for (int i = 0; i < 8; ++i) {
    int s = SS[ty*8 + i];
    hv[i] = *(const uint4*)&hAb[(size_t)s * HD + tx*8];
  }
  __syncthreads();
  if (tid < 128) {
    int rr = rank + ((tid >= 64) ? sScal[2] : 0);
    if (head) { segstart[rr] = tid; segdst[rr] = SD[tid]; }
  }
  if (tid == 64) sScal[3] = sScal[2] + __popcll(bal);

  const int lrow = lane & 15, lk = lane >> 4;
  f32x4 acc[2][8];
#pragma unroll
  for (int rt = 0; rt < 2; ++rt)
#pragma unroll
    for (int ct = 0; ct < 8; ++ct) acc[rt][ct] = (f32x4){0.f, 0.f, 0.f, 0.f};

#pragma unroll
  for (int kt = 0; kt < 4; ++kt) {
    bf16x8 a[2];
#pragma unroll
    for (int rt = 0; rt < 2; ++rt) {
      int e = w4*32 + rt*16 + lrow;
      int kb = kt*4 + lk;
      a[rt] = *(const bf16x8*)&Tw[e * 128 + ((kb ^ (e & 7)) << 3)];
    }
#pragma unroll
    for (int cg = 0; cg < 2; ++cg) {
      bf16x8 bq[4];
#pragma unroll
      for (int c4 = 0; c4 < 4; ++c4)
        bq[c4] = *(const bf16x8*)&Wpk[(size_t)(((kt*8 + cg*4 + c4) * 64) + lane) * 8];
#pragma unroll
      for (int rt = 0; rt < 2; ++rt)
#pragma unroll
        for (int c4 = 0; c4 < 4; ++c4)
          acc[rt][cg*4 + c4] = __builtin_amdgcn_mfma_f32_16x16x32_bf16(
              a[rt], bq[c4], acc[rt][cg*4 + c4], 0, 0, 0);
    }
  }
  __syncthreads();

#pragma unroll
  for (int rt = 0; rt < 2; ++rt) {
    int ebase = w4*32 + rt*16 + lk*4;
#pragma unroll
    for (int ct = 0; ct < 8; ++ct) {
      int c = ct*16 + lrow;
      Tw[(ebase+0)*128 + c] = (unsigned short)rne16(acc[rt][ct][0]);
      Tw[(ebase+1)*128 + c] = (unsigned short)rne16(acc[rt][ct][1]);
      Tw[(ebase+2)*128 + c] = (unsigned short)rne16(acc[rt][ct][2]);
      Tw[(ebase+3)*128 + c] = (unsigned short)rne16(acc[rt][ct][3]);
    }
  }
  __syncthreads();

  {
    float4 u0 = *(const float4*)&ub[tx*8];
    float4 u1 = *(const float4*)&ub[tx*8+4];
    float ubv[8] = {u0.x,u0.y,u0.z,u0.w,u1.x,u1.y,u1.z,u1.w};
#pragma unroll
    for (int i = 0; i < 8; ++i) {
      int row = ty*8 + i;
      uint4 uv = *(const uint4*)&Tw[row * 128 + tx*8];
      float uvv[8] = {blo(uv.x),bhi(uv.x),blo(uv.y),bhi(uv.y),
                      blo(uv.z),bhi(uv.z),blo(uv.w),bhi(uv.w)};
      float hvv[8] = {blo(hv[i].x),bhi(hv[i].x),blo(hv[i].y),bhi(hv[i].y),
                      blo(hv[i].z),bhi(hv[i].z),blo(hv[i].w),bhi(hv[i].w)};
      float p[8];
#pragma unroll
      for (int j = 0; j < 8; ++j) {
        float v = uvv[j] + hvv[j] + ubv[j];
        p[j] = v > 0.f ? v : 0.f;
      }
      uint4 w;
      w.x = bfpack(p[0], p[1]); w.y = bfpack(p[2], p[3]);
      w.z = bfpack(p[4], p[5]); w.w = bfpack(p[6], p[7]);
      *(uint4*)&Tw[row * 128 + tx*8] = w;
    }
  }
  __syncthreads();

  {
    const int nseg = sScal[3];
    const int dprev = sScal[0], dnext = sScal[1];
    for (int s = w4; s < nseg; s += 4) {
      int dst = segdst[s];
      if (dst < 0) continue;
      int r0 = segstart[s];
      int r1 = (s + 1 < nseg) ? segstart[s + 1] : 128;
      float sx = 0.f, sy = 0.f;
      for (int rr = r0; rr < r1; ++rr) {
        unsigned v = *(const unsigned*)&Tw[rr * 128 + lane * 2];
        sx += blo(v); sy += bhi(v);
      }
      float* pp = &Pagg[(size_t)dst * HD + lane * 2];
      if (dst == dprev || dst == dnext) {
        atomicAdd(pp, sx);
        atomicAdd(pp + 1, sy);
      } else {
        float2 st = {sx, sy};
        *(float2*)pp = st;
      }
    }
  }
}

// ---- readout phase 1: y[node] = relu(h@l1w+l1b)@l2w + l2b  (MFMA) ----------
__global__ __launch_bounds__(256, 4) void readout1_k(
    const float* __restrict__ h, const float* __restrict__ l1w,
    const float* __restrict__ l1b, const float* __restrict__ l2w,
    const float* __restrict__ l2b, float* __restrict__ ybuf, int n)
{
  __shared__ __align__(16) unsigned short Bh[8192];   // [128 x 64] B-frag
  const int tid = threadIdx.x;
  const int lane = tid & 63, w4 = tid >> 6;
  const int lrow = lane & 15, lk = lane >> 4;
  const int m0 = blockIdx.x * 128;

  // stage l1w: group g = (kt*4+ct)*64+ln
  for (int it = 0; it < 4; ++it) {
    int g = tid + it * 256;              // [0,1024)
    int kt = g >> 8, ct = (g >> 6) & 3, ln = g & 63;
    int row = kt * 32 + ((ln >> 4) << 3);
    int col = ct * 16 + (ln & 15);
    unsigned short h8[8];
#pragma unroll
    for (int e = 0; e < 8; ++e) h8[e] = (unsigned short)rne16(l1w[(size_t)(row + e) * 64 + col]);
    uint4 p = {(unsigned)h8[0] | ((unsigned)h8[1] << 16),
               (unsigned)h8[2] | ((unsigned)h8[3] << 16),
               (unsigned)h8[4] | ((unsigned)h8[5] << 16),
               (unsigned)h8[6] | ((unsigned)h8[7] << 16)};
    *(uint4*)&Bh[g * 8] = p;
  }
  __syncthreads();

  f32x4 acc[2][4];
#pragma unroll
  for (int rt = 0; rt < 2; ++rt)
#pragma unroll
    for (int ct = 0; ct < 4; ++ct) acc[rt][ct] = (f32x4){0.f, 0.f, 0.f, 0.f};

#pragma unroll
  for (int kt = 0; kt < 4; ++kt) {
    int k0 = kt * 32 + lk * 8;
    bf16x8 a[2];
#pragma unroll
    for (int rt = 0; rt < 2; ++rt) {
      int row = m0 + w4 * 32 + rt * 16 + lrow;
      unsigned short h8[8] = {0,0,0,0,0,0,0,0};
      if (row < n) {
        float4 v0 = *(const float4*)&h[(size_t)row * HD + k0];
        float4 v1 = *(const float4*)&h[(size_t)row * HD + k0 + 4];
        float v[8] = {v0.x,v0.y,v0.z,v0.w,v1.x,v1.y,v1.z,v1.w};
#pragma unroll
        for (int e = 0; e < 8; ++e) h8[e] = (unsigned short)rne16(v[e]);
      }
      a[rt] = *(bf16x8*)h8;
    }
#pragma unroll
    for (int ct = 0; ct < 4; ++ct) {
      bf16x8 b = *(const bf16x8*)&Bh[(((kt * 4 + ct) * 64) + lane) * 8];
#pragma unroll
      for (int rt = 0; rt < 2; ++rt)
        acc[rt][ct] = __builtin_amdgcn_mfma_f32_16x16x32_bf16(a[rt], b, acc[rt][ct], 0, 0, 0);
    }
  }

  const float l2b0 = l2b[0];
#pragma unroll
  for (int rt = 0; rt < 2; ++rt) {
    float yp[4] = {0.f, 0.f, 0.f, 0.f};
#pragma unroll
    for (int ct = 0; ct < 4; ++ct) {
      int col = ct * 16 + lrow;
      float b1 = l1b[col], w2 = l2w[col];
#pragma unroll
      for (int reg = 0; reg < 4; ++reg) {
        float z = acc[rt][ct][reg] + b1;
        yp[reg] = fmaf(z > 0.f ? z : 0.f, w2, yp[reg]);
      }
    }
#pragma unroll
    for (int reg = 0; reg < 4; ++reg) {
#pragma unroll
      for (int off = 1; off < 16; off <<= 1) yp[reg] += __shfl_xor(yp[reg], off);
      int row = m0 + w4 * 32 + rt * 16 + lk * 4 + reg;
      if (lrow == 0 && row < n) ybuf[row] = yp[reg] + l2b0;
    }
  }
}

// ---- readout phase 2: segment-sum ybuf by sorted batch ---------------------
__global__ void readout2_k(const float* __restrict__ ybuf, const int* __restrict__ batch,
                           float* __restrict__ out, int n) {
  int t = blockIdx.x * 256 + threadIdx.x;
  int base = t * 8;
  if (base >= n) return;
  int bprev = batch[base];
  float s = ybuf[base];
  for (int i = 1; i < 8; ++i) {
    int idx = base + i;
    if (idx >= n) break;
    int bb = batch[idx];
    if (bb != bprev) { atomicAdd(&out[bprev], s); s = 0.f; bprev = bb; }
    s += ybuf[idx];
  }
  atomicAdd(&out[bprev], s);
}

extern "C" void kernel_launch(void* const* d_in, const int* in_sizes, int n_in,
                              void* d_out, int out_size, void* d_ws, size_t ws_size,
                              hipStream_t stream) {
  const float* x     = (const float*)d_in[0];
  const float* pos   = (const float*)d_in[1];
  const int*   ei    = (const int*)d_in[2];
  const int*   batch = (const int*)d_in[3];
  const float* nw1   = (const float*)d_in[4];
  const float* nb1   = (const float*)d_in[5];
  const float* nw2   = (const float*)d_in[6];
  const float* nb2   = (const float*)d_in[7];
  const float* m1w1  = (const float*)d_in[8];
  const float* m1b1  = (const float*)d_in[9];
  const float* m1w2  = (const float*)d_in[10];
  const float* m1b2  = (const float*)d_in[11];
  const float* m2w1  = (const float*)d_in[12];
  const float* m2b1  = (const float*)d_in[13];
  const float* m2w2  = (const float*)d_in[14];
  const float* m2b2  = (const float*)d_in[15];
  const float* m3w1  = (const float*)d_in[16];
  const float* m3b1  = (const float*)d_in[17];
  const float* m3w2  = (const float*)d_in[18];
  const float* m3b2  = (const float*)d_in[19];
  const float* l1w   = (const float*)d_in[20];
  const float* l1b   = (const float*)d_in[21];
  const float* l2w   = (const float*)d_in[22];
  const float* l2b   = (const float*)d_in[23];

  const int N = in_sizes[0];
  const int E = in_sizes[2] / 2;
  const int L = in_sizes[8] / (256 * 128);

  float* h    = (float*)d_ws;                     // [N,128]
  float* buf2 = h    + (size_t)N * HD;            // tmp [N,128]
  float* Pagg = buf2 + (size_t)N * HD;            // [N,128]
  unsigned int* spk = (unsigned int*)(Pagg + (size_t)N * HD);  // [E]
  int*   cnt  = (int*)(spk + E);                  // [N]
  float* invd = (float*)(cnt + N);                // [N]
  float* Wf   = invd + N;                         // [L,128,128]
  float* ub   = Wf + (size_t)L * 128 * 128;       // [L,128]
  float* Wm   = ub + (size_t)L * 128;             // [L,128,128]
  float* bfold= Wm + (size_t)L * 128 * 128;       // [L,128]
  unsigned short* hAb = (unsigned short*)(bfold + (size_t)L * 128);  // [N,128] bf16
  unsigned short* Wpk = hAb + (size_t)N * HD;     // [L,16384]
  float* ybuf = (float*)(Wpk + (size_t)L * 16384);// [N]

  hipMemsetAsync(cnt, 0, (size_t)N * sizeof(int), stream);
  hipMemsetAsync(d_out, 0, (size_t)out_size * sizeof(float), stream);

  count_k<<<(E + 255) / 256, 256, 0, stream>>>(ei, cnt, E);
  scan_k<<<1, 1024, 0, stream>>>(cnt, invd, N);
  scatter_k<<<(E + 255) / 256, 256, 0, stream>>>(ei, cnt, spk, E);
  fold_all_k<<<dim3(128, L, 2), 128, 0, stream>>>(m3w2, m2w1, m3b2, m2b1,
                                                  m2w2, m1w1, m2b2, Wf, ub, Wm, bfold);
  pack_k<<<dim3(64, L), 256, 0, stream>>>(Wf, Wpk);

  const int gblk = (N + 127) / 128;
  // h = relu(x*nw1+nb1) @ nw2 + nb2   (node_init fused into A-load)
  gemm_mfma<4, false, false, false, false, true><<<gblk, 256, 0, stream>>>(
      x, nullptr, nullptr, nw2, nullptr, nb2, nullptr, nw1, nb1, h, N);

  const int nwg = (E + 127) / 128;
  for (int l = 0; l < L; ++l) {
    const float* W2a = m2w1 + (size_t)l * 256 * 128;              // rows 0..127
    const float* W1b = m1w1 + (size_t)l * 256 * 128 + 128 * 128;  // rows 128..255
    // hAb = bf16(h @ W2a)
    gemm_mfma<4, false, false, false, true, false><<<gblk, 256, 0, stream>>>(
        h, nullptr, nullptr, W2a, nullptr, nullptr, nullptr, nullptr, nullptr,
        (float*)hAb, N);
    hipMemsetAsync(Pagg, 0, (size_t)N * HD * sizeof(float), stream);
    edge_k<<<nwg, 256, 0, stream>>>(
        spk, pos, hAb,
        m3w1 + (size_t)l * 3 * 128, m3b1 + (size_t)l * 128,
        Wpk + (size_t)l * 16384, ub + (size_t)l * 128,
        Pagg, E, nwg);
    // tmp = relu((Pagg*invd)@Wm + [deg>0]*bf + h@W1b + m1b1)
    gemm_mfma<8, true, true, true, false, false><<<gblk, 256, 0, stream>>>(
        Pagg, h, invd, Wm + (size_t)l * 128 * 128, W1b,
        m1b1 + (size_t)l * 128, bfold + (size_t)l * 128, nullptr, nullptr, buf2, N);
    // h = relu(tmp @ m1w2 + m1b2)
    gemm_mfma<4, true, false, false, false, false><<<gblk, 256, 0, stream>>>(
        buf2, nullptr, nullptr, m1w2 + (size_t)l * 128 * 128, nullptr,
        m1b2 + (size_t)l * 128, nullptr, nullptr, nullptr, h, N);
  }

  readout1_k<<<gblk, 256, 0, stream>>>(h, l1w, l1b, l2w, l2b, ybuf, N);
  readout2_k<<<(N + 2047) / 2048, 256, 0, stream>>>(ybuf, batch, (float*)d_out, N);
}

// Round 6
// 703.093 us; speedup vs baseline: 10.5439x; 1.1126x over previous
//
#include <hip/hip_runtime.h>

#define HD 128

typedef __attribute__((ext_vector_type(8))) short bf16x8;
typedef __attribute__((ext_vector_type(4))) float f32x4;

// ---- bf16 helpers ----------------------------------------------------------
__device__ __forceinline__ unsigned rne16(float x) {
  unsigned u = __builtin_bit_cast(unsigned, x);
  return (u + 0x7fffu + ((u >> 16) & 1u)) >> 16;
}
__device__ __forceinline__ unsigned bfpack(float a, float b) {
  return rne16(a) | (rne16(b) << 16);
}
__device__ __forceinline__ float blo(unsigned u) { return __builtin_bit_cast(float, u << 16); }
__device__ __forceinline__ float bhi(unsigned u) { return __builtin_bit_cast(float, u & 0xffff0000u); }
__device__ __forceinline__ float bval(unsigned h16) { return __builtin_bit_cast(float, h16 << 16); }

__device__ __forceinline__ void bsplit(float v, unsigned short& hi, unsigned short& lo) {
  unsigned h = rne16(v);
  hi = (unsigned short)h;
  lo = (unsigned short)rne16(v - bval(h));
}

// ---- degree count ----------------------------------------------------------
__global__ void count_k(const int* __restrict__ ei, int* __restrict__ cnt, int E) {
  int e = blockIdx.x * 256 + threadIdx.x;
  if (e < E) atomicAdd(&cnt[ei[E + e]], 1);
}

// ---- 3-phase multi-block exclusive scan ------------------------------------
__global__ __launch_bounds__(512) void scanA_k(const int* __restrict__ cnt,
                                               int* __restrict__ bsum, int n) {
  __shared__ int ws[8];
  const int tid = threadIdx.x, lane = tid & 63, wid = tid >> 6;
  int i = blockIdx.x * 512 + tid;
  int v = (i < n) ? cnt[i] : 0;
#pragma unroll
  for (int off = 32; off > 0; off >>= 1) v += __shfl_xor(v, off);
  if (lane == 0) ws[wid] = v;
  __syncthreads();
  if (tid == 0) {
    int s = 0;
#pragma unroll
    for (int w = 0; w < 8; ++w) s += ws[w];
    bsum[blockIdx.x] = s;
  }
}

__global__ __launch_bounds__(128) void scanB_k(int* __restrict__ bsum, int nb) {
  __shared__ int w2[2];
  const int tid = threadIdx.x, lane = tid & 63, wid = tid >> 6;
  int v = (tid < nb) ? bsum[tid] : 0;
  int s = v;
#pragma unroll
  for (int off = 1; off < 64; off <<= 1) {
    int u = __shfl_up(s, off);
    if (lane >= off) s += u;
  }
  if (lane == 63) w2[wid] = s;
  __syncthreads();
  int add = (wid == 1) ? w2[0] : 0;
  if (tid < nb) bsum[tid] = s - v + add;
}

__global__ __launch_bounds__(512) void scanC_k(int* __restrict__ cnt, float* __restrict__ invd,
                                               const int* __restrict__ bsum, int n) {
  __shared__ int ws[8];
  const int tid = threadIdx.x, lane = tid & 63, wid = tid >> 6;
  int i = blockIdx.x * 512 + tid;
  int v = (i < n) ? cnt[i] : 0;
  int s = v;
#pragma unroll
  for (int off = 1; off < 64; off <<= 1) {
    int u = __shfl_up(s, off);
    if (lane >= off) s += u;
  }
  if (lane == 63) ws[wid] = s;
  __syncthreads();
  int wadd = 0;
  for (int w = 0; w < wid; ++w) wadd += ws[w];
  if (i < n) {
    cnt[i] = s - v + wadd + bsum[blockIdx.x];
    invd[i] = v > 0 ? 1.f / (float)v : 0.f;
  }
}

// ---- scatter into dst-sorted order: spk[p] = src | (dst<<16) ---------------
__global__ void scatter_k(const int* __restrict__ ei, int* __restrict__ cur,
                          unsigned int* __restrict__ spk, int E) {
  int e = blockIdx.x * 256 + threadIdx.x;
  if (e >= E) return;
  int s = ei[e], d = ei[E + e];
  int p = atomicAdd(&cur[d], 1);
  spk[p] = (unsigned int)s | ((unsigned int)d << 16);
}

// ---- weight folding --------------------------------------------------------
__global__ void fold_all_k(const float* __restrict__ m3w2, const float* __restrict__ m2w1,
                           const float* __restrict__ m3b2, const float* __restrict__ m2b1,
                           const float* __restrict__ m2w2, const float* __restrict__ m1w1,
                           const float* __restrict__ m2b2,
                           float* __restrict__ Wf, float* __restrict__ ub,
                           float* __restrict__ Wm, float* __restrict__ bf) {
  const int k = blockIdx.x, l = blockIdx.y, mode = blockIdx.z, c = threadIdx.x;
  const float *A, *B, *bA, *badd;
  float *O, *ob;
  if (mode == 0) {
    A = m3w2 + (size_t)l * 128 * 128;
    B = m2w1 + (size_t)l * 256 * 128 + 128 * 128;
    bA = m3b2 + (size_t)l * 128; badd = m2b1 + (size_t)l * 128;
    O = Wf + (size_t)l * 128 * 128; ob = ub + (size_t)l * 128;
  } else {
    A = m2w2 + (size_t)l * 128 * 128;
    B = m1w1 + (size_t)l * 256 * 128;
    bA = m2b2 + (size_t)l * 128; badd = nullptr;
    O = Wm + (size_t)l * 128 * 128; ob = bf + (size_t)l * 128;
  }
  float s = 0.f;
  for (int r = 0; r < 128; ++r) s = fmaf(A[k * 128 + r], B[r * 128 + c], s);
  O[k * 128 + c] = s;
  if (k == 0) {
    float t = badd ? badd[c] : 0.f;
    for (int r = 0; r < 128; ++r) t = fmaf(bA[r], B[r * 128 + c], t);
    ob[c] = t;
  }
}

// ---- pack Wf into bf16 MFMA B-fragment order (edge kernel, hi only) --------
__global__ void pack_k(const float* __restrict__ Wf, unsigned short* __restrict__ Wpk) {
  int l = blockIdx.y;
  int flat = blockIdx.x * 256 + threadIdx.x;
  int e = flat & 7, l6 = (flat >> 3) & 63, ct = (flat >> 9) & 7, kt = flat >> 12;
  int row = kt * 32 + ((l6 >> 4) << 3) + e;
  int col = ct * 16 + (l6 & 15);
  Wpk[(size_t)l * 16384 + flat] =
      (unsigned short)rne16(Wf[(size_t)l * 16384 + row * 128 + col]);
}

// ---- pack node-GEMM weights into hi/lo B-fragment buffers (one launch) -----
struct PDesc { const float* w0; const float* w1; unsigned short* out; int kt; };
struct PArgs { PDesc d[10]; };

__global__ void packw_k(PArgs pa) {
  PDesc de = pa.d[blockIdx.y];
  int flat = blockIdx.x * 256 + threadIdx.x;
  int tot = de.kt * 4096;
  if (flat >= tot) return;
  int e = flat & 7, ln = (flat >> 3) & 63, ct = (flat >> 9) & 7, kt = flat >> 12;
  int row = kt * 32 + ((ln >> 4) << 3) + e;
  int col = ct * 16 + (ln & 15);
  float v = (row < 128) ? de.w0[(size_t)row * 128 + col]
                        : de.w1[(size_t)(row - 128) * 128 + col];
  unsigned short hi, lo;
  bsplit(v, hi, lo);
  de.out[flat] = hi;
  de.out[tot + flat] = lo;
}

// ---- node GEMM via MFMA, hi/lo split, B-frags from global (no LDS) ---------
// out[M][128] = act( [sc.*in0 | in1] @ Wn + bias + [sc>0]*bias2 )
// AINIT: A row r = relu(in0[r]*aw[k] + ab[k])
template<int KT, bool RELU, bool SCALE0, bool BIAS2, bool OUTBF16, bool AINIT>
__global__ __launch_bounds__(256) void gemm_mfma(
    const float* __restrict__ in0, const float* __restrict__ in1,
    const float* __restrict__ sc, const unsigned short* __restrict__ Wn,
    const float* __restrict__ bias, const float* __restrict__ bias2,
    const float* __restrict__ aw, const float* __restrict__ ab,
    float* __restrict__ out, int M)
{
  const int tid = threadIdx.x;
  const int lane = tid & 63, w4 = tid >> 6;
  const int lrow = lane & 15, lk = lane >> 4;
  const int m0 = blockIdx.x * 128;
  const unsigned short* __restrict__ Wlo = Wn + KT * 4096;

  int rown[2];
  bool valid[2];
  float scl[2], xv[2];
#pragma unroll
  for (int rt = 0; rt < 2; ++rt) {
    rown[rt] = m0 + w4 * 32 + rt * 16 + lrow;
    valid[rt] = rown[rt] < M;
    scl[rt] = (SCALE0 && valid[rt]) ? sc[rown[rt]] : 1.f;
    xv[rt] = (AINIT && valid[rt]) ? in0[rown[rt]] : 0.f;
  }

  f32x4 acc[2][8];
#pragma unroll
  for (int rt = 0; rt < 2; ++rt)
#pragma unroll
    for (int ct = 0; ct < 8; ++ct) acc[rt][ct] = (f32x4){0.f, 0.f, 0.f, 0.f};

#pragma unroll
  for (int ktg = 0; ktg < KT; ++ktg) {
    const int k0 = ktg * 32 + lk * 8;
    bf16x8 ah[2], al[2];
    if (AINIT) {
      float4 a0 = *(const float4*)&aw[k0];
      float4 a1 = *(const float4*)&aw[k0 + 4];
      float4 b0 = *(const float4*)&ab[k0];
      float4 b1 = *(const float4*)&ab[k0 + 4];
      float awv[8] = {a0.x,a0.y,a0.z,a0.w,a1.x,a1.y,a1.z,a1.w};
      float abv[8] = {b0.x,b0.y,b0.z,b0.w,b1.x,b1.y,b1.z,b1.w};
#pragma unroll
      for (int rt = 0; rt < 2; ++rt) {
        unsigned short h8[8], l8[8];
#pragma unroll
        for (int e = 0; e < 8; ++e) {
          float v = fmaf(xv[rt], awv[e], abv[e]);
          v = v > 0.f ? v : 0.f;
          bsplit(v, h8[e], l8[e]);
        }
        ah[rt] = *(bf16x8*)h8; al[rt] = *(bf16x8*)l8;
      }
    } else {
#pragma unroll
      for (int rt = 0; rt < 2; ++rt) {
        float v[8] = {0,0,0,0,0,0,0,0};
        if (valid[rt]) {
          const float* base = (KT == 8 && k0 >= 128)
                              ? (in1 + (size_t)rown[rt] * HD + (k0 - 128))
                              : (in0 + (size_t)rown[rt] * HD + k0);
          float4 v0 = *(const float4*)base;
          float4 v1 = *(const float4*)(base + 4);
          v[0]=v0.x; v[1]=v0.y; v[2]=v0.z; v[3]=v0.w;
          v[4]=v1.x; v[5]=v1.y; v[6]=v1.z; v[7]=v1.w;
          if (SCALE0 && k0 < 128) {
#pragma unroll
            for (int e = 0; e < 8; ++e) v[e] *= scl[rt];
          }
        }
        unsigned short h8[8], l8[8];
#pragma unroll
        for (int e = 0; e < 8; ++e) bsplit(v[e], h8[e], l8[e]);
        ah[rt] = *(bf16x8*)h8; al[rt] = *(bf16x8*)l8;
      }
    }
#pragma unroll
    for (int ct = 0; ct < 8; ++ct) {
      const size_t boff = (size_t)(((ktg * 8 + ct) * 64) + lane) * 8;
      bf16x8 bh = *(const bf16x8*)&Wn[boff];
      bf16x8 bl = *(const bf16x8*)&Wlo[boff];
#pragma unroll
      for (int rt = 0; rt < 2; ++rt) {
        acc[rt][ct] = __builtin_amdgcn_mfma_f32_16x16x32_bf16(ah[rt], bh, acc[rt][ct], 0, 0, 0);
        acc[rt][ct] = __builtin_amdgcn_mfma_f32_16x16x32_bf16(al[rt], bh, acc[rt][ct], 0, 0, 0);
        acc[rt][ct] = __builtin_amdgcn_mfma_f32_16x16x32_bf16(ah[rt], bl, acc[rt][ct], 0, 0, 0);
      }
    }
  }

#pragma unroll
  for (int rt = 0; rt < 2; ++rt) {
    int rbase = m0 + w4 * 32 + rt * 16 + lk * 4;
    float m2[4];
#pragma unroll
    for (int reg = 0; reg < 4; ++reg) {
      int row = rbase + reg;
      m2[reg] = (BIAS2 && row < M && sc[row] > 0.f) ? 1.f : 0.f;
    }
#pragma unroll
    for (int ct = 0; ct < 8; ++ct) {
      int col = ct * 16 + lrow;
      float bv = bias ? bias[col] : 0.f;
      float b2v = BIAS2 ? bias2[col] : 0.f;
#pragma unroll
      for (int reg = 0; reg < 4; ++reg) {
        int row = rbase + reg;
        if (row < M) {
          float v = acc[rt][ct][reg] + bv + m2[reg] * b2v;
          if (RELU && v < 0.f) v = 0.f;
          if (OUTBF16) ((unsigned short*)out)[(size_t)row * HD + col] = (unsigned short)rne16(v);
          else out[(size_t)row * HD + col] = v;
        }
      }
    }
  }
}

// ---- zero Pagg rows that receive atomics (segment crosses a block boundary) -
__global__ void bzero_k(const unsigned int* __restrict__ spk, float* __restrict__ Pagg,
                        int nwg) {
  int g = blockIdx.x * 256 + threadIdx.x;
  int idx = g >> 5, l32 = g & 31;
  if (idx >= nwg - 1) return;
  int dst = (int)(spk[(idx + 1) * 128] >> 16);
  *(float4*)&Pagg[(size_t)dst * HD + l32 * 4] = (float4){0.f, 0.f, 0.f, 0.f};
}

// ---- fused edge kernel (unchanged from round 4/5) --------------------------
__global__ __launch_bounds__(256, 4) void edge_k(
    const unsigned int* __restrict__ spk, const float* __restrict__ pos,
    const unsigned short* __restrict__ hAb,
    const float* __restrict__ w31, const float* __restrict__ b31,
    const unsigned short* __restrict__ Wpk, const float* __restrict__ ub,
    float* __restrict__ Pagg, int E, int nwg)
{
  __shared__ __align__(16) unsigned short Tw[128 * 128];
  __shared__ int SS[128];
  __shared__ int SD[128];
  __shared__ int segstart[132];
  __shared__ int segdst[132];
  __shared__ int sScal[4];
  const int tid = threadIdx.x;
  const int lane = tid & 63, w4 = tid >> 6;

  int b = blockIdx.x;
  int q = nwg >> 3, r = nwg & 7;
  int xcd = b & 7, sub = b >> 3;
  int wg = (xcd < r ? xcd * (q + 1) : r * (q + 1) + (xcd - r) * q) + sub;
  const int e0 = wg * 128;

  {
    int el = tid & 127;
    int p = e0 + el;
    int s = 0, d = -1;
    float d0 = 0.f, d1 = 0.f, d2 = 0.f;
    if (p < E) {
      unsigned int pk = spk[p];
      s = (int)(pk & 0xffffu);
      d = (int)(pk >> 16);
      d0 = pos[(size_t)s*3+0] - pos[(size_t)d*3+0];
      d1 = pos[(size_t)s*3+1] - pos[(size_t)d*3+1];
      d2 = pos[(size_t)s*3+2] - pos[(size_t)d*3+2];
    }
    if (tid < 128) { SS[tid] = s; SD[tid] = d; }
    if (tid == 0) sScal[0] = (e0 > 0) ? (int)(spk[e0-1] >> 16) : -2;
    if (tid == 1) sScal[1] = (e0 + 128 < E) ? (int)(spk[e0+128] >> 16) : -2;
    int k0 = (tid >> 7) * 64;
    int swz = el & 7;
#pragma unroll
    for (int g = 0; g < 8; ++g) {
      int kb = (k0 >> 3) + g;
      float v[8];
#pragma unroll
      for (int j = 0; j < 8; ++j) {
        int k = k0 + g*8 + j;
        float t = fmaf(d0, w31[k], fmaf(d1, w31[128+k], fmaf(d2, w31[256+k], b31[k])));
        v[j] = t > 0.f ? t : 0.f;
      }
      uint4 w;
      w.x = bfpack(v[0], v[1]); w.y = bfpack(v[2], v[3]);
      w.z = bfpack(v[4], v[5]); w.w = bfpack(v[6], v[7]);
      *(uint4*)&Tw[el * 128 + ((kb ^ swz) << 3)] = w;
    }
  }
  __syncthreads();

  bool head = false;
  if (tid < 128) {
    int d = SD[tid];
    head = (tid == 0) ? true : (d != SD[tid - 1]);
  }
  unsigned long long bal = __ballot(head);
  int rank = __popcll(bal & ((1ull << lane) - 1));
  if (tid == 0) sScal[2] = 0;
  if (tid == 63) sScal[2] = rank + (head ? 1 : 0);

  const int ty = tid >> 4, tx = tid & 15;
  uint4 hv[8];
#pragma unroll
  for (int i = 0; i < 8; ++i) {
    int s = SS[ty*8 + i];
    hv[i] = *(const uint4*)&hAb[(size_t)s * HD + tx*8];
  }
  __syncthreads();
  if (tid < 128) {
    int rr = rank + ((tid >= 64) ? sScal[2] : 0);
    if (head) { segstart[rr] = tid; segdst[rr] = SD[tid]; }
  }
  if (tid == 64) sScal[3] = sScal[2] + __popcll(bal);

  const int lrow = lane & 15, lk = lane >> 4;
  f32x4 acc[2][8];
#pragma unroll
  for (int rt = 0; rt < 2; ++rt)
#pragma unroll
    for (int ct = 0; ct < 8; ++ct) acc[rt][ct] = (f32x4){0.f, 0.f, 0.f, 0.f};

#pragma unroll
  for (int kt = 0; kt < 4; ++kt) {
    bf16x8 a[2];
#pragma unroll
    for (int rt = 0; rt < 2; ++rt) {
      int e = w4*32 + rt*16 + lrow;
      int kb = kt*4 + lk;
      a[rt] = *(const bf16x8*)&Tw[e * 128 + ((kb ^ (e & 7)) << 3)];
    }
#pragma unroll
    for (int cg = 0; cg < 2; ++cg) {
      bf16x8 bq[4];
#pragma unroll
      for (int c4 = 0; c4 < 4; ++c4)
        bq[c4] = *(const bf16x8*)&Wpk[(size_t)(((kt*8 + cg*4 + c4) * 64) + lane) * 8];
#pragma unroll
      for (int rt = 0; rt < 2; ++rt)
#pragma unroll
        for (int c4 = 0; c4 < 4; ++c4)
          acc[rt][cg*4 + c4] = __builtin_amdgcn_mfma_f32_16x16x32_bf16(
              a[rt], bq[c4], acc[rt][cg*4 + c4], 0, 0, 0);
    }
  }
  __syncthreads();

#pragma unroll
  for (int rt = 0; rt < 2; ++rt) {
    int ebase = w4*32 + rt*16 + lk*4;
#pragma unroll
    for (int ct = 0; ct < 8; ++ct) {
      int c = ct*16 + lrow;
      Tw[(ebase+0)*128 + c] = (unsigned short)rne16(acc[rt][ct][0]);
      Tw[(ebase+1)*128 + c] = (unsigned short)rne16(acc[rt][ct][1]);
      Tw[(ebase+2)*128 + c] = (unsigned short)rne16(acc[rt][ct][2]);
      Tw[(ebase+3)*128 + c] = (unsigned short)rne16(acc[rt][ct][3]);
    }
  }
  __syncthreads();

  {
    float4 u0 = *(const float4*)&ub[tx*8];
    float4 u1 = *(const float4*)&ub[tx*8+4];
    float ubv[8] = {u0.x,u0.y,u0.z,u0.w,u1.x,u1.y,u1.z,u1.w};
#pragma unroll
    for (int i = 0; i < 8; ++i) {
      int row = ty*8 + i;
      uint4 uv = *(const uint4*)&Tw[row * 128 + tx*8];
      float uvv[8] = {blo(uv.x),bhi(uv.x),blo(uv.y),bhi(uv.y),
                      blo(uv.z),bhi(uv.z),blo(uv.w),bhi(uv.w)};
      float hvv[8] = {blo(hv[i].x),bhi(hv[i].x),blo(hv[i].y),bhi(hv[i].y),
                      blo(hv[i].z),bhi(hv[i].z),blo(hv[i].w),bhi(hv[i].w)};
      float p[8];
#pragma unroll
      for (int j = 0; j < 8; ++j) {
        float v = uvv[j] + hvv[j] + ubv[j];
        p[j] = v > 0.f ? v : 0.f;
      }
      uint4 w;
      w.x = bfpack(p[0], p[1]); w.y = bfpack(p[2], p[3]);
      w.z = bfpack(p[4], p[5]); w.w = bfpack(p[6], p[7]);
      *(uint4*)&Tw[row * 128 + tx*8] = w;
    }
  }
  __syncthreads();

  {
    const int nseg = sScal[3];
    const int dprev = sScal[0], dnext = sScal[1];
    for (int s = w4; s < nseg; s += 4) {
      int dst = segdst[s];
      if (dst < 0) continue;
      int r0 = segstart[s];
      int r1 = (s + 1 < nseg) ? segstart[s + 1] : 128;
      float sx = 0.f, sy = 0.f;
      for (int rr = r0; rr < r1; ++rr) {
        unsigned v = *(const unsigned*)&Tw[rr * 128 + lane * 2];
        sx += blo(v); sy += bhi(v);
      }
      float* pp = &Pagg[(size_t)dst * HD + lane * 2];
      if (dst == dprev || dst == dnext) {
        atomicAdd(pp, sx);
        atomicAdd(pp + 1, sy);
      } else {
        float2 st = {sx, sy};
        *(float2*)pp = st;
      }
    }
  }
}

// ---- readout phase 1: y[node] = relu(h@l1w+l1b)@l2w + l2b  (MFMA) ----------
__global__ __launch_bounds__(256, 4) void readout1_k(
    const float* __restrict__ h, const float* __restrict__ l1w,
    const float* __restrict__ l1b, const float* __restrict__ l2w,
    const float* __restrict__ l2b, float* __restrict__ ybuf, int n)
{
  __shared__ __align__(16) unsigned short Bh[8192];
  const int tid = threadIdx.x;
  const int lane = tid & 63, w4 = tid >> 6;
  const int lrow = lane & 15, lk = lane >> 4;
  const int m0 = blockIdx.x * 128;

  for (int it = 0; it < 4; ++it) {
    int g = tid + it * 256;
    int kt = g >> 8, ct = (g >> 6) & 3, ln = g & 63;
    int row = kt * 32 + ((ln >> 4) << 3);
    int col = ct * 16 + (ln & 15);
    unsigned short h8[8];
#pragma unroll
    for (int e = 0; e < 8; ++e) h8[e] = (unsigned short)rne16(l1w[(size_t)(row + e) * 64 + col]);
    uint4 p = {(unsigned)h8[0] | ((unsigned)h8[1] << 16),
               (unsigned)h8[2] | ((unsigned)h8[3] << 16),
               (unsigned)h8[4] | ((unsigned)h8[5] << 16),
               (unsigned)h8[6] | ((unsigned)h8[7] << 16)};
    *(uint4*)&Bh[g * 8] = p;
  }
  __syncthreads();

  f32x4 acc[2][4];
#pragma unroll
  for (int rt = 0; rt < 2; ++rt)
#pragma unroll
    for (int ct = 0; ct < 4; ++ct) acc[rt][ct] = (f32x4){0.f, 0.f, 0.f, 0.f};

#pragma unroll
  for (int kt = 0; kt < 4; ++kt) {
    int k0 = kt * 32 + lk * 8;
    bf16x8 a[2];
#pragma unroll
    for (int rt = 0; rt < 2; ++rt) {
      int row = m0 + w4 * 32 + rt * 16 + lrow;
      unsigned short h8[8] = {0,0,0,0,0,0,0,0};
      if (row < n) {
        float4 v0 = *(const float4*)&h[(size_t)row * HD + k0];
        float4 v1 = *(const float4*)&h[(size_t)row * HD + k0 + 4];
        float v[8] = {v0.x,v0.y,v0.z,v0.w,v1.x,v1.y,v1.z,v1.w};
#pragma unroll
        for (int e = 0; e < 8; ++e) h8[e] = (unsigned short)rne16(v[e]);
      }
      a[rt] = *(bf16x8*)h8;
    }
#pragma unroll
    for (int ct = 0; ct < 4; ++ct) {
      bf16x8 b = *(const bf16x8*)&Bh[(((kt * 4 + ct) * 64) + lane) * 8];
#pragma unroll
      for (int rt = 0; rt < 2; ++rt)
        acc[rt][ct] = __builtin_amdgcn_mfma_f32_16x16x32_bf16(a[rt], b, acc[rt][ct], 0, 0, 0);
    }
  }

  const float l2b0 = l2b[0];
#pragma unroll
  for (int rt = 0; rt < 2; ++rt) {
    float yp[4] = {0.f, 0.f, 0.f, 0.f};
#pragma unroll
    for (int ct = 0; ct < 4; ++ct) {
      int col = ct * 16 + lrow;
      float b1 = l1b[col], w2 = l2w[col];
#pragma unroll
      for (int reg = 0; reg < 4; ++reg) {
        float z = acc[rt][ct][reg] + b1;
        yp[reg] = fmaf(z > 0.f ? z : 0.f, w2, yp[reg]);
      }
    }
#pragma unroll
    for (int reg = 0; reg < 4; ++reg) {
#pragma unroll
      for (int off = 1; off < 16; off <<= 1) yp[reg] += __shfl_xor(yp[reg], off);
      int row = m0 + w4 * 32 + rt * 16 + lk * 4 + reg;
      if (lrow == 0 && row < n) ybuf[row] = yp[reg] + l2b0;
    }
  }
}

// ---- readout phase 2: segment-sum ybuf by sorted batch ---------------------
__global__ void readout2_k(const float* __restrict__ ybuf, const int* __restrict__ batch,
                           float* __restrict__ out, int n) {
  int t = blockIdx.x * 256 + threadIdx.x;
  int base = t * 8;
  if (base >= n) return;
  int bprev = batch[base];
  float s = ybuf[base];
  for (int i = 1; i < 8; ++i) {
    int idx = base + i;
    if (idx >= n) break;
    int bb = batch[idx];
    if (bb != bprev) { atomicAdd(&out[bprev], s); s = 0.f; bprev = bb; }
    s += ybuf[idx];
  }
  atomicAdd(&out[bprev], s);
}

extern "C" void kernel_launch(void* const* d_in, const int* in_sizes, int n_in,
                              void* d_out, int out_size, void* d_ws, size_t ws_size,
                              hipStream_t stream) {
  const float* x     = (const float*)d_in[0];
  const float* pos   = (const float*)d_in[1];
  const int*   ei    = (const int*)d_in[2];
  const int*   batch = (const int*)d_in[3];
  const float* nw1   = (const float*)d_in[4];
  const float* nb1   = (const float*)d_in[5];
  const float* nw2   = (const float*)d_in[6];
  const float* nb2   = (const float*)d_in[7];
  const float* m1w1  = (const float*)d_in[8];
  const float* m1b1  = (const float*)d_in[9];
  const float* m1w2  = (const float*)d_in[10];
  const float* m1b2  = (const float*)d_in[11];
  const float* m2w1  = (const float*)d_in[12];
  const float* m2b1  = (const float*)d_in[13];
  const float* m2w2  = (const float*)d_in[14];
  const float* m2b2  = (const float*)d_in[15];
  const float* m3w1  = (const float*)d_in[16];
  const float* m3b1  = (const float*)d_in[17];
  const float* m3w2  = (const float*)d_in[18];
  const float* m3b2  = (const float*)d_in[19];
  const float* l1w   = (const float*)d_in[20];
  const float* l1b   = (const float*)d_in[21];
  const float* l2w   = (const float*)d_in[22];
  const float* l2b   = (const float*)d_in[23];

  const int N = in_sizes[0];
  const int E = in_sizes[2] / 2;
  const int L = in_sizes[8] / (256 * 128);

  float* h    = (float*)d_ws;                     // [N,128]
  float* buf2 = h    + (size_t)N * HD;            // tmp [N,128]
  float* Pagg = buf2 + (size_t)N * HD;            // [N,128]
  unsigned int* spk = (unsigned int*)(Pagg + (size_t)N * HD);  // [E]
  int*   cnt  = (int*)(spk + E);                  // [N]
  float* invd = (float*)(cnt + N);                // [N]
  float* Wf   = invd + N;                         // [L,128,128]
  float* ub   = Wf + (size_t)L * 128 * 128;       // [L,128]
  float* Wm   = ub + (size_t)L * 128;             // [L,128,128]
  float* bfold= Wm + (size_t)L * 128 * 128;       // [L,128]
  unsigned short* hAb = (unsigned short*)(bfold + (size_t)L * 128);  // [N,128] bf16
  unsigned short* Wpk = hAb + (size_t)N * HD;     // [L,16384]
  float* ybuf = (float*)(Wpk + (size_t)L * 16384);// [N]
  int*   bsum = (int*)(ybuf + N);                 // [128]
  unsigned short* WnBase = (unsigned short*)(bsum + 128);
  // packed node weights: init(32768) + per layer {W2a 32768, cat 65536, w2 32768}
  unsigned short* WnInit = WnBase;
  unsigned short* WnW2a[3], *WnCat[3], *WnW2[3];
  {
    unsigned short* p = WnBase + 32768;
    for (int l = 0; l < 3; ++l) {
      WnW2a[l] = p; p += 32768;
      WnCat[l] = p; p += 65536;
      WnW2[l]  = p; p += 32768;
    }
  }

  hipMemsetAsync(cnt, 0, (size_t)N * sizeof(int), stream);
  hipMemsetAsync(d_out, 0, (size_t)out_size * sizeof(float), stream);

  count_k<<<(E + 255) / 256, 256, 0, stream>>>(ei, cnt, E);
  const int nsb = (N + 511) / 512;
  scanA_k<<<nsb, 512, 0, stream>>>(cnt, bsum, N);
  scanB_k<<<1, 128, 0, stream>>>(bsum, nsb);
  scanC_k<<<nsb, 512, 0, stream>>>(cnt, invd, bsum, N);
  scatter_k<<<(E + 255) / 256, 256, 0, stream>>>(ei, cnt, spk, E);
  fold_all_k<<<dim3(128, L, 2), 128, 0, stream>>>(m3w2, m2w1, m3b2, m2b1,
                                                  m2w2, m1w1, m2b2, Wf, ub, Wm, bfold);
  pack_k<<<dim3(64, L), 256, 0, stream>>>(Wf, Wpk);

  {
    PArgs pa;
    pa.d[0] = {nw2, nullptr, WnInit, 4};
    for (int l = 0; l < L; ++l) {
      pa.d[1 + l * 3] = {m2w1 + (size_t)l * 256 * 128, nullptr, WnW2a[l], 4};
      pa.d[2 + l * 3] = {Wm + (size_t)l * 128 * 128,
                         m1w1 + (size_t)l * 256 * 128 + 128 * 128, WnCat[l], 8};
      pa.d[3 + l * 3] = {m1w2 + (size_t)l * 128 * 128, nullptr, WnW2[l], 4};
    }
    packw_k<<<dim3(128, 1 + L * 3), 256, 0, stream>>>(pa);
  }

  const int gblk = (N + 127) / 128;
  // h = relu(x*nw1+nb1) @ nw2 + nb2
  gemm_mfma<4, false, false, false, false, true><<<gblk, 256, 0, stream>>>(
      x, nullptr, nullptr, WnInit, nb2, nullptr, nw1, nb1, h, N);

  const int nwg = (E + 127) / 128;
  const int nbz = ((nwg - 1) * 32 + 255) / 256;
  for (int l = 0; l < L; ++l) {
    // hAb = bf16(h @ W2a)
    gemm_mfma<4, false, false, false, true, false><<<gblk, 256, 0, stream>>>(
        h, nullptr, nullptr, WnW2a[l], nullptr, nullptr, nullptr, nullptr,
        (float*)hAb, N);
    bzero_k<<<nbz, 256, 0, stream>>>(spk, Pagg, nwg);
    edge_k<<<nwg, 256, 0, stream>>>(
        spk, pos, hAb,
        m3w1 + (size_t)l * 3 * 128, m3b1 + (size_t)l * 128,
        Wpk + (size_t)l * 16384, ub + (size_t)l * 128,
        Pagg, E, nwg);
    // tmp = relu((Pagg*invd)@Wm + [deg>0]*bf + h@W1b + m1b1)
    gemm_mfma<8, true, true, true, false, false><<<gblk, 256, 0, stream>>>(
        Pagg, h, invd, WnCat[l],
        m1b1 + (size_t)l * 128, bfold + (size_t)l * 128, nullptr, nullptr, buf2, N);
    // h = relu(tmp @ m1w2 + m1b2)
    gemm_mfma<4, true, false, false, false, false><<<gblk, 256, 0, stream>>>(
        buf2, nullptr, nullptr, WnW2[l],
        m1b2 + (size_t)l * 128, nullptr, nullptr, nullptr, h, N);
  }

  readout1_k<<<gblk, 256, 0, stream>>>(h, l1w, l1b, l2w, l2b, ybuf, N);
  readout2_k<<<(N + 2047) / 2048, 256, 0, stream>>>(ybuf, batch, (float*)d_out, N);
}